// Round 1
// baseline (629.154 us; speedup 1.0000x reference)
//
#include <hip/hip_runtime.h>
#include <stdint.h>

// ---------------- types & helpers ----------------
typedef float  f32x4 __attribute__((ext_vector_type(4)));
typedef short  s16x8 __attribute__((ext_vector_type(8)));
typedef short  s16x4 __attribute__((ext_vector_type(4)));

__device__ __forceinline__ float bf2f(short s) {
  unsigned u = ((unsigned)(unsigned short)s) << 16;
  return __builtin_bit_cast(float, u);
}
__device__ __forceinline__ short f2bf(float f) {
  unsigned u = __builtin_bit_cast(unsigned, f);
  u = u + 0x7fffu + ((u >> 16) & 1u);   // RNE
  return (short)(u >> 16);
}
// async global->LDS, 16B per lane (dest must be wave-uniform base + lane*16)
__device__ __forceinline__ void g2l16(const void* g, void* l) {
  __builtin_amdgcn_global_load_lds((const __attribute__((address_space(1))) void*)g,
                                   (__attribute__((address_space(3))) void*)l,
                                   16, 0, 0);
}

// ---------------- prep: transpose 1024x1024 f32 weights -> bf16 [N][K] ----------------
__global__ void wtrans_kernel(const float* __restrict__ Wq, const float* __restrict__ Wk,
                              const float* __restrict__ Wv, const float* __restrict__ Wd,
                              short* __restrict__ WqT, short* __restrict__ WkT,
                              short* __restrict__ WvT, short* __restrict__ WdT) {
  __shared__ float tile[64][65];          // +1 pad: conflict-free transpose
  const float* src; short* dst;
  switch (blockIdx.z) {
    case 0: src = Wq; dst = WqT; break;
    case 1: src = Wk; dst = WkT; break;
    case 2: src = Wv; dst = WvT; break;
    default: src = Wd; dst = WdT; break;
  }
  int k0 = blockIdx.y * 64;   // source row block (k)
  int n0 = blockIdx.x * 64;   // source col block (n)
  int tid = threadIdx.x;
#pragma unroll
  for (int p = 0; p < 4; ++p) {
    int idx = p * 1024 + tid * 4;
    int r = idx >> 6, c = idx & 63;
    f32x4 v = *(const f32x4*)(src + (size_t)(k0 + r) * 1024 + n0 + c);
    tile[r][c + 0] = v[0]; tile[r][c + 1] = v[1];
    tile[r][c + 2] = v[2]; tile[r][c + 3] = v[3];
  }
  __syncthreads();
#pragma unroll
  for (int p = 0; p < 2; ++p) {
    int idx = p * 2048 + tid * 8;
    int r = idx >> 6, c = idx & 63;       // out row n, out col k
    s16x8 o;
#pragma unroll
    for (int i = 0; i < 8; ++i) o[i] = f2bf(tile[c + i][r]);
    *(s16x8*)(dst + (size_t)(n0 + r) * 1024 + k0 + c) = o;
  }
}

// Wcb [1024][16] -> WcbT bf16 [16][1024]; mixing [16][1024] -> bf16
__global__ void smallconv_kernel(const float* __restrict__ Wcb, const float* __restrict__ mixing,
                                 short* __restrict__ WcbT, short* __restrict__ mixbf) {
  int idx = blockIdx.x * 256 + threadIdx.x;   // 0..32767
  if (idx < 16384) {
    int h = idx >> 10, d = idx & 1023;
    WcbT[idx] = f2bf(Wcb[d * 16 + h]);
  } else {
    int j = idx - 16384;
    mixbf[j] = f2bf(mixing[j]);
  }
}

// gather rows: from (f32 + bf16) and to (bf16)
__global__ void gather_kernel(const float* __restrict__ hidden, const int* __restrict__ fpos,
                              const int* __restrict__ tpos, float* __restrict__ from_f,
                              short* __restrict__ from_bf, short* __restrict__ to_bf) {
  int row = blockIdx.x;
  int c = threadIdx.x * 4;
  if (blockIdx.y == 0) {
    int src = fpos[row] & 511;
    f32x4 v = *(const f32x4*)(hidden + (size_t)src * 1024 + c);
    *(f32x4*)(from_f + (size_t)row * 1024 + c) = v;
    s16x4 o;
#pragma unroll
    for (int i = 0; i < 4; ++i) o[i] = f2bf(v[i]);
    *(s16x4*)(from_bf + (size_t)row * 1024 + c) = o;
  } else {
    int src = tpos[row] & 511;
    f32x4 v = *(const f32x4*)(hidden + (size_t)src * 1024 + c);
    s16x4 o;
#pragma unroll
    for (int i = 0; i < 4; ++i) o[i] = f2bf(v[i]);
    *(s16x4*)(to_bf + (size_t)row * 1024 + c) = o;
  }
}

// ---------------- GEMM: C = A[M,1024] @ B^T[N,1024]  (m97-style 128x128 tile) ----------------
// MODE 0: C bf16 [M][N]
// MODE 1: C bf16 transposed [N][M], + bias[N]   (for vT)
// MODE 2: C f32 [M][N] = acc + bias[N] + resid[M][N]
template <int MODE>
__global__ __launch_bounds__(256, 2)
void gemm_bt(const short* __restrict__ A, const short* __restrict__ B,
             const float* __restrict__ bias, const float* __restrict__ resid,
             void* __restrict__ Cout, int M, int N) {
  __shared__ __align__(16) short As[128][64];
  __shared__ __align__(16) short Bs[128][64];
  int m0 = blockIdx.x * 128, n0 = blockIdx.y * 128;
  int tid = threadIdx.x;
  int w = tid >> 6, l = tid & 63;
  int wr = w >> 1, wc = w & 1;            // 2x2 wave grid, 64x64 each
  f32x4 acc[4][4] = {};
  for (int k0 = 0; k0 < 1024; k0 += 64) {
    __syncthreads();
#pragma unroll
    for (int i = 0; i < 4; ++i) {
      int off = i * 4096 + tid * 16;      // byte offset within 16KB tile
      int r = off >> 7, cb_ = off & 127;
      g2l16(A + ((size_t)(m0 + r) << 10) + k0 + (cb_ >> 1), (short*)As + (off >> 1));
      g2l16(B + ((size_t)(n0 + r) << 10) + k0 + (cb_ >> 1), (short*)Bs + (off >> 1));
    }
    __syncthreads();
#pragma unroll
    for (int ks = 0; ks < 2; ++ks) {
      s16x8 af[4], bfr[4];
#pragma unroll
      for (int m = 0; m < 4; ++m)
        af[m] = *(const s16x8*)&As[wr * 64 + m * 16 + (l & 15)][ks * 32 + (l >> 4) * 8];
#pragma unroll
      for (int n = 0; n < 4; ++n)
        bfr[n] = *(const s16x8*)&Bs[wc * 64 + n * 16 + (l & 15)][ks * 32 + (l >> 4) * 8];
#pragma unroll
      for (int m = 0; m < 4; ++m)
#pragma unroll
        for (int n = 0; n < 4; ++n)
          acc[m][n] = __builtin_amdgcn_mfma_f32_16x16x32_bf16(af[m], bfr[n], acc[m][n], 0, 0, 0);
    }
  }
  int lr = (l >> 4) * 4, lc = l & 15;
#pragma unroll
  for (int m = 0; m < 4; ++m)
#pragma unroll
    for (int n = 0; n < 4; ++n) {
      int row = m0 + wr * 64 + m * 16 + lr;
      int col = n0 + wc * 64 + n * 16 + lc;
      if (MODE == 0) {
        short* C = (short*)Cout;
#pragma unroll
        for (int r = 0; r < 4; ++r) C[(size_t)(row + r) * N + col] = f2bf(acc[m][n][r]);
      } else if (MODE == 1) {
        short* C = (short*)Cout;          // [N][M]
        float b = bias[col];
        s16x4 o;
#pragma unroll
        for (int r = 0; r < 4; ++r) o[r] = f2bf(acc[m][n][r] + b);
        *(s16x4*)(C + (size_t)col * M + row) = o;
      } else {
        float* C = (float*)Cout;
        float b = bias[col];
#pragma unroll
        for (int r = 0; r < 4; ++r)
          C[(size_t)(row + r) * N + col] = acc[m][n][r] + b + resid[(size_t)(row + r) * N + col];
      }
    }
}

// ---------------- content bias: cb[h][t] = sum_d to[t,d]*Wcb[d,h] ----------------
__global__ void cb_kernel(const short* __restrict__ to_bf, const short* __restrict__ WcbT,
                          float* __restrict__ cb) {
  int wid = (blockIdx.x * 256 + threadIdx.x) >> 6;   // 0..32767
  int lane = threadIdx.x & 63;
  int t = wid >> 4, h = wid & 15;
  const short* xr = to_bf + (size_t)t * 1024 + lane * 16;
  const short* wr_ = WcbT + (size_t)h * 1024 + lane * 16;
  float acc = 0.f;
#pragma unroll
  for (int j = 0; j < 2; ++j) {
    s16x8 x = *(const s16x8*)(xr + j * 8);
    s16x8 w_ = *(const s16x8*)(wr_ + j * 8);
#pragma unroll
    for (int i = 0; i < 8; ++i) acc += bf2f(x[i]) * bf2f(w_[i]);
  }
#pragma unroll
  for (int s = 32; s; s >>= 1) acc += __shfl_xor(acc, s);
  if (lane == 0) cb[(size_t)h * 2048 + t] = acc;
}

// optional: qmix[h][f][d] = q[f][d]*mix[h][d]  (lets attention stage q via global_load_lds)
__global__ void qmix_kernel(const short* __restrict__ q_bf, const short* __restrict__ mixbf,
                            short* __restrict__ qmix) {
  int f = blockIdx.x, h = blockIdx.y;
  int c = threadIdx.x * 4;
  s16x4 qv = *(const s16x4*)(q_bf + ((size_t)f << 10) + c);
  s16x4 mv = *(const s16x4*)(mixbf + ((size_t)h << 10) + c);
  s16x4 o;
#pragma unroll
  for (int i = 0; i < 4; ++i) o[i] = f2bf(bf2f(qv[i]) * bf2f(mv[i]));
  *(s16x4*)(qmix + (((size_t)h * 2048 + f) << 10) + c) = o;
}

// ---------------- flash attention: block = (64 f-rows, head) ----------------
template <bool QMIX>
__global__ __launch_bounds__(256, 2)
void attn_kernel(const short* __restrict__ q_bf, const short* __restrict__ k_bf,
                 const short* __restrict__ vT, const short* __restrict__ mixbf,
                 const float* __restrict__ cb, const short* __restrict__ qmix,
                 short* __restrict__ ctx_bf) {
  __shared__ __align__(16) short qm[64][64];      // 8KB  (q*mix chunk)
  __shared__ __align__(16) short kt[128][64];     // 16KB (k chunk)
  __shared__ __align__(16) short vt[64][128];     // 16KB (vT tile: [dh][t])
  __shared__ __align__(16) short pt[4][16][128];  // 16KB (per-wave P)
  __shared__ __align__(16) float cbl[2048];       // 8KB
  int f0 = blockIdx.x * 64, h = blockIdx.y;
  int tid = threadIdx.x, w = tid >> 6, l = tid & 63;
  int lr = l >> 4, lc = l & 15;
  for (int i = tid; i < 512; i += 256)
    *(f32x4*)&cbl[i * 4] = *(const f32x4*)(cb + ((size_t)h * 2048) + i * 4);
  float m_run[4], l_run[4];
#pragma unroll
  for (int r = 0; r < 4; ++r) { m_run[r] = -1e30f; l_run[r] = 0.f; }
  f32x4 ctx[4] = {};
  const short* qmh = QMIX ? (qmix + (((size_t)h * 2048 + f0) << 10)) : (const short*)0;

  for (int t0 = 0; t0 < 2048; t0 += 128) {
    f32x4 sacc[8] = {};
    for (int k0 = 0; k0 < 1024; k0 += 64) {
      __syncthreads();                      // prior reads of qm/kt (and vt at k0==0) done
      if (QMIX) {
#pragma unroll
        for (int i = 0; i < 2; ++i) {
          int off = i * 4096 + tid * 16;
          int r = off >> 7, cb_ = off & 127;
          g2l16(qmh + ((size_t)r << 10) + k0 + (cb_ >> 1), (short*)qm + (off >> 1));
        }
      } else {
#pragma unroll
        for (int i = 0; i < 2; ++i) {
          int off = i * 4096 + tid * 16;
          int r = off >> 7, c = (off & 127) >> 1;
          s16x8 qv = *(const s16x8*)(q_bf + ((size_t)(f0 + r) << 10) + k0 + c);
          s16x8 mv = *(const s16x8*)(mixbf + ((size_t)h << 10) + k0 + c);
          s16x8 o;
#pragma unroll
          for (int e = 0; e < 8; ++e) o[e] = f2bf(bf2f(qv[e]) * bf2f(mv[e]));
          *(s16x8*)&qm[r][c] = o;
        }
      }
#pragma unroll
      for (int i = 0; i < 4; ++i) {
        int off = i * 4096 + tid * 16;
        int r = off >> 7, cb_ = off & 127;
        g2l16(k_bf + ((size_t)(t0 + r) << 10) + k0 + (cb_ >> 1), (short*)kt + (off >> 1));
      }
      if (k0 == 0) {
#pragma unroll
        for (int i = 0; i < 4; ++i) {
          int off = i * 4096 + tid * 16;
          int r = off >> 8, cb_ = off & 255;
          g2l16(vT + ((size_t)(h * 64 + r) << 11) + t0 + (cb_ >> 1), (short*)vt + (off >> 1));
        }
      }
      __syncthreads();                      // staging visible (vmcnt+lgkm drained)
#pragma unroll
      for (int ks = 0; ks < 2; ++ks) {
        s16x8 af = *(const s16x8*)&qm[w * 16 + lc][ks * 32 + lr * 8];
#pragma unroll
        for (int n = 0; n < 8; ++n) {
          s16x8 bfr = *(const s16x8*)&kt[n * 16 + lc][ks * 32 + lr * 8];
          sacc[n] = __builtin_amdgcn_mfma_f32_16x16x32_bf16(af, bfr, sacc[n], 0, 0, 0);
        }
      }
    }
    // ---- online softmax (wave-parallel; lane owns rows lr*4+r, col lc of each 16-col frag)
    float p[8][4];
    float tm[4] = {-1e30f, -1e30f, -1e30f, -1e30f};
#pragma unroll
    for (int n = 0; n < 8; ++n) {
      float cbv = cbl[t0 + n * 16 + lc];
#pragma unroll
      for (int r = 0; r < 4; ++r) {
        float s = (sacc[n][r] + cbv) * 0.125f;
        p[n][r] = s;
        tm[r] = fmaxf(tm[r], s);
      }
    }
#pragma unroll
    for (int s_ = 1; s_ < 16; s_ <<= 1)
#pragma unroll
      for (int r = 0; r < 4; ++r) tm[r] = fmaxf(tm[r], __shfl_xor(tm[r], s_));
    float ts[4] = {0.f, 0.f, 0.f, 0.f};
#pragma unroll
    for (int r = 0; r < 4; ++r) {
      float mold = m_run[r];
      float mnew = fmaxf(mold, tm[r]);
      float corr = __expf(mold - mnew);
      m_run[r] = mnew;
      l_run[r] *= corr;
#pragma unroll
      for (int n2 = 0; n2 < 4; ++n2) ctx[n2][r] *= corr;
#pragma unroll
      for (int n = 0; n < 8; ++n) {
        float e = __expf(p[n][r] - mnew);
        p[n][r] = e;
        ts[r] += e;
      }
    }
#pragma unroll
    for (int s_ = 1; s_ < 16; s_ <<= 1)
#pragma unroll
      for (int r = 0; r < 4; ++r) ts[r] += __shfl_xor(ts[r], s_);
#pragma unroll
    for (int r = 0; r < 4; ++r) l_run[r] += ts[r];
    // ---- P -> per-wave LDS (C-frag layout -> A-frag layout)
#pragma unroll
    for (int n = 0; n < 8; ++n)
#pragma unroll
      for (int r = 0; r < 4; ++r)
        pt[w][lr * 4 + r][n * 16 + lc] = f2bf(p[n][r]);
    // ---- PV
#pragma unroll
    for (int ks = 0; ks < 4; ++ks) {
      s16x8 af = *(const s16x8*)&pt[w][lc][ks * 32 + lr * 8];
#pragma unroll
      for (int n2 = 0; n2 < 4; ++n2) {
        s16x8 bfr = *(const s16x8*)&vt[n2 * 16 + lc][ks * 32 + lr * 8];
        ctx[n2] = __builtin_amdgcn_mfma_f32_16x16x32_bf16(af, bfr, ctx[n2], 0, 0, 0);
      }
    }
  }
#pragma unroll
  for (int n2 = 0; n2 < 4; ++n2)
#pragma unroll
    for (int r = 0; r < 4; ++r) {
      float o = ctx[n2][r] / l_run[r];
      ctx_bf[(size_t)(f0 + w * 16 + lr * 4 + r) * 1024 + h * 64 + n2 * 16 + lc] = f2bf(o);
    }
}

// ---------------- LayerNorm over rows of res ----------------
__global__ void ln_kernel(const float* __restrict__ res, const float* __restrict__ gamma,
                          const float* __restrict__ beta, float* __restrict__ out) {
  int row = blockIdx.x, tid = threadIdx.x;
  f32x4 x = *(const f32x4*)(res + ((size_t)row << 10) + tid * 4);
  float s = x[0] + x[1] + x[2] + x[3];
  float s2 = x[0] * x[0] + x[1] * x[1] + x[2] * x[2] + x[3] * x[3];
#pragma unroll
  for (int m = 1; m < 64; m <<= 1) { s += __shfl_xor(s, m); s2 += __shfl_xor(s2, m); }
  __shared__ float red[8];
  int w = tid >> 6, l = tid & 63;
  if (l == 0) { red[w] = s; red[4 + w] = s2; }
  __syncthreads();
  s = red[0] + red[1] + red[2] + red[3];
  s2 = red[4] + red[5] + red[6] + red[7];
  float mu = s * (1.f / 1024.f);
  float var = s2 * (1.f / 1024.f) - mu * mu;
  float rstd = rsqrtf(var + 1e-5f);
  f32x4 o;
#pragma unroll
  for (int i = 0; i < 4; ++i)
    o[i] = (x[i] - mu) * rstd * gamma[tid * 4 + i] + beta[tid * 4 + i];
  *(f32x4*)(out + ((size_t)row << 10) + tid * 4) = o;
}

// ---------------- launch ----------------
extern "C" void kernel_launch(void* const* d_in, const int* in_sizes, int n_in,
                              void* d_out, int out_size, void* d_ws, size_t ws_size,
                              hipStream_t stream) {
  const float* hidden = (const float*)d_in[0];
  const int*   fpos   = (const int*)d_in[1];
  const int*   tpos   = (const int*)d_in[2];
  const float* Wq     = (const float*)d_in[3];
  const float* Wk     = (const float*)d_in[4];
  const float* Wcb    = (const float*)d_in[5];
  const float* Wv     = (const float*)d_in[6];
  const float* bv     = (const float*)d_in[7];
  const float* mixing = (const float*)d_in[8];
  const float* Wd     = (const float*)d_in[9];
  const float* bd     = (const float*)d_in[10];
  const float* gamma  = (const float*)d_in[11];
  const float* beta   = (const float*)d_in[12];

  char* p = (char*)d_ws;
  auto alloc = [&](size_t bytes) { char* r = p; p += (bytes + 255) & ~(size_t)255; return r; };
  float* from_f  = (float*)alloc((size_t)2048 * 1024 * 4);
  short* from_bf = (short*)alloc((size_t)2048 * 1024 * 2);
  short* to_bf   = (short*)alloc((size_t)2048 * 1024 * 2);
  short* WqT     = (short*)alloc((size_t)1024 * 1024 * 2);
  short* WkT     = (short*)alloc((size_t)1024 * 1024 * 2);
  short* WvT     = (short*)alloc((size_t)1024 * 1024 * 2);
  short* WdT     = (short*)alloc((size_t)1024 * 1024 * 2);
  short* WcbT    = (short*)alloc((size_t)16 * 1024 * 2);
  short* mixbf   = (short*)alloc((size_t)16 * 1024 * 2);
  short* q_bf    = (short*)alloc((size_t)2048 * 1024 * 2);
  short* k_bf    = (short*)alloc((size_t)2048 * 1024 * 2);
  short* vTb     = (short*)alloc((size_t)1024 * 2048 * 2);
  float* cbb     = (float*)alloc((size_t)16 * 2048 * 4);
  short* ctx_bf  = (short*)alloc((size_t)2048 * 1024 * 2);
  float* resb    = (float*)alloc((size_t)2048 * 1024 * 4);
  size_t used = (size_t)(p - (char*)d_ws);
  short* qmixb = (short*)p;
  bool use_qmix = ws_size >= used + (size_t)16 * 2048 * 1024 * 2;

  wtrans_kernel<<<dim3(16, 16, 4), 256, 0, stream>>>(Wq, Wk, Wv, Wd, WqT, WkT, WvT, WdT);
  smallconv_kernel<<<128, 256, 0, stream>>>(Wcb, mixing, WcbT, mixbf);
  gather_kernel<<<dim3(2048, 2), 256, 0, stream>>>(hidden, fpos, tpos, from_f, from_bf, to_bf);
  gemm_bt<0><<<dim3(16, 8), 256, 0, stream>>>(from_bf, WqT, nullptr, nullptr, q_bf, 2048, 1024);
  gemm_bt<0><<<dim3(16, 8), 256, 0, stream>>>(to_bf, WkT, nullptr, nullptr, k_bf, 2048, 1024);
  gemm_bt<1><<<dim3(16, 8), 256, 0, stream>>>(to_bf, WvT, bv, nullptr, vTb, 2048, 1024);
  cb_kernel<<<8192, 256, 0, stream>>>(to_bf, WcbT, cbb);
  if (use_qmix) {
    qmix_kernel<<<dim3(2048, 16), 256, 0, stream>>>(q_bf, mixbf, qmixb);
    attn_kernel<true><<<dim3(32, 16), 256, 0, stream>>>(q_bf, k_bf, vTb, mixbf, cbb, qmixb, ctx_bf);
  } else {
    attn_kernel<false><<<dim3(32, 16), 256, 0, stream>>>(q_bf, k_bf, vTb, mixbf, cbb, nullptr, ctx_bf);
  }
  gemm_bt<2><<<dim3(16, 8), 256, 0, stream>>>(ctx_bf, WdT, bd, from_f, resb, 2048, 1024);
  ln_kernel<<<2048, 256, 0, stream>>>(resb, gamma, beta, (float*)d_out);
}

// Round 2
// 561.236 us; speedup vs baseline: 1.1210x; 1.1210x over previous
//
#include <hip/hip_runtime.h>
#include <stdint.h>

// ---------------- types & helpers ----------------
typedef float  f32x4 __attribute__((ext_vector_type(4)));
typedef short  s16x8 __attribute__((ext_vector_type(8)));
typedef short  s16x4 __attribute__((ext_vector_type(4)));

__device__ __forceinline__ float bf2f(short s) {
  unsigned u = ((unsigned)(unsigned short)s) << 16;
  return __builtin_bit_cast(float, u);
}
__device__ __forceinline__ short f2bf(float f) {
  unsigned u = __builtin_bit_cast(unsigned, f);
  u = u + 0x7fffu + ((u >> 16) & 1u);   // RNE
  return (short)(u >> 16);
}
// async global->LDS, 16B per lane (dest: wave-uniform base + lane*16)
__device__ __forceinline__ void g2l16(const void* g, void* l) {
  __builtin_amdgcn_global_load_lds((const __attribute__((address_space(1))) void*)g,
                                   (__attribute__((address_space(3))) void*)l,
                                   16, 0, 0);
}

// ---------------- prep: transpose 1024x1024 f32 weights -> bf16 [N][K] ----------------
__global__ void wtrans_kernel(const float* __restrict__ Wq, const float* __restrict__ Wk,
                              const float* __restrict__ Wv, const float* __restrict__ Wd,
                              short* __restrict__ WqT, short* __restrict__ WkT,
                              short* __restrict__ WvT, short* __restrict__ WdT) {
  __shared__ float tile[64][65];
  const float* src; short* dst;
  switch (blockIdx.z) {
    case 0: src = Wq; dst = WqT; break;
    case 1: src = Wk; dst = WkT; break;
    case 2: src = Wv; dst = WvT; break;
    default: src = Wd; dst = WdT; break;
  }
  int k0 = blockIdx.y * 64;
  int n0 = blockIdx.x * 64;
  int tid = threadIdx.x;
#pragma unroll
  for (int p = 0; p < 4; ++p) {
    int idx = p * 1024 + tid * 4;
    int r = idx >> 6, c = idx & 63;
    f32x4 v = *(const f32x4*)(src + (size_t)(k0 + r) * 1024 + n0 + c);
    tile[r][c + 0] = v[0]; tile[r][c + 1] = v[1];
    tile[r][c + 2] = v[2]; tile[r][c + 3] = v[3];
  }
  __syncthreads();
#pragma unroll
  for (int p = 0; p < 2; ++p) {
    int idx = p * 2048 + tid * 8;
    int r = idx >> 6, c = idx & 63;
    s16x8 o;
#pragma unroll
    for (int i = 0; i < 8; ++i) o[i] = f2bf(tile[c + i][r]);
    *(s16x8*)(dst + (size_t)(n0 + r) * 1024 + k0 + c) = o;
  }
}

// Wcb [1024][16] -> WcbT bf16 [16][1024]; mixing [16][1024] -> bf16
__global__ void smallconv_kernel(const float* __restrict__ Wcb, const float* __restrict__ mixing,
                                 short* __restrict__ WcbT, short* __restrict__ mixbf) {
  int idx = blockIdx.x * 256 + threadIdx.x;
  if (idx < 16384) {
    int h = idx >> 10, d = idx & 1023;
    WcbT[idx] = f2bf(Wcb[d * 16 + h]);
  } else {
    int j = idx - 16384;
    mixbf[j] = f2bf(mixing[j]);
  }
}

// gather rows: from (f32 + bf16) and to (bf16)
__global__ void gather_kernel(const float* __restrict__ hidden, const int* __restrict__ fpos,
                              const int* __restrict__ tpos, float* __restrict__ from_f,
                              short* __restrict__ from_bf, short* __restrict__ to_bf) {
  int row = blockIdx.x;
  int c = threadIdx.x * 4;
  if (blockIdx.y == 0) {
    int src = fpos[row] & 511;
    f32x4 v = *(const f32x4*)(hidden + (size_t)src * 1024 + c);
    *(f32x4*)(from_f + (size_t)row * 1024 + c) = v;
    s16x4 o;
#pragma unroll
    for (int i = 0; i < 4; ++i) o[i] = f2bf(v[i]);
    *(s16x4*)(from_bf + (size_t)row * 1024 + c) = o;
  } else {
    int src = tpos[row] & 511;
    f32x4 v = *(const f32x4*)(hidden + (size_t)src * 1024 + c);
    s16x4 o;
#pragma unroll
    for (int i = 0; i < 4; ++i) o[i] = f2bf(v[i]);
    *(s16x4*)(to_bf + (size_t)row * 1024 + c) = o;
  }
}

// ---------------- GEMM: C = A[M,1024] @ B^T[N,1024]  (128x128 tile) ----------------
// MODE 0: C bf16 [M][N]
// MODE 1: C bf16 transposed [N][M], + bias[N], t-swizzled (row ^= (col&15)<<3)  (vT)
// MODE 2: C f32 [M][N] = acc + bias[N] + resid[M][N]
// MODE 3: C bf16 [M][N], col-swizzled (col ^= (row&7)<<3)  (k for attn staging)
template <int MODE>
__global__ __launch_bounds__(256, 2)
void gemm_bt(const short* __restrict__ A, const short* __restrict__ B,
             const float* __restrict__ bias, const float* __restrict__ resid,
             void* __restrict__ Cout, int M, int N) {
  __shared__ __align__(16) short As[128][64];
  __shared__ __align__(16) short Bs[128][64];
  int m0 = blockIdx.x * 128, n0 = blockIdx.y * 128;
  int tid = threadIdx.x;
  int w = tid >> 6, l = tid & 63;
  int wr = w >> 1, wc = w & 1;
  f32x4 acc[4][4] = {};
  for (int k0 = 0; k0 < 1024; k0 += 64) {
    __syncthreads();
#pragma unroll
    for (int i = 0; i < 4; ++i) {
      int off = i * 4096 + tid * 16;
      int r = off >> 7, cb_ = off & 127;
      g2l16(A + ((size_t)(m0 + r) << 10) + k0 + (cb_ >> 1), (short*)As + (off >> 1));
      g2l16(B + ((size_t)(n0 + r) << 10) + k0 + (cb_ >> 1), (short*)Bs + (off >> 1));
    }
    __syncthreads();
#pragma unroll
    for (int ks = 0; ks < 2; ++ks) {
      s16x8 af[4], bfr[4];
#pragma unroll
      for (int m = 0; m < 4; ++m)
        af[m] = *(const s16x8*)&As[wr * 64 + m * 16 + (l & 15)][ks * 32 + (l >> 4) * 8];
#pragma unroll
      for (int n = 0; n < 4; ++n)
        bfr[n] = *(const s16x8*)&Bs[wc * 64 + n * 16 + (l & 15)][ks * 32 + (l >> 4) * 8];
#pragma unroll
      for (int m = 0; m < 4; ++m)
#pragma unroll
        for (int n = 0; n < 4; ++n)
          acc[m][n] = __builtin_amdgcn_mfma_f32_16x16x32_bf16(af[m], bfr[n], acc[m][n], 0, 0, 0);
    }
  }
  int lr = (l >> 4) * 4, lc = l & 15;
#pragma unroll
  for (int m = 0; m < 4; ++m)
#pragma unroll
    for (int n = 0; n < 4; ++n) {
      int row = m0 + wr * 64 + m * 16 + lr;
      int col = n0 + wc * 64 + n * 16 + lc;
      if (MODE == 0) {
        short* C = (short*)Cout;
#pragma unroll
        for (int r = 0; r < 4; ++r) C[(size_t)(row + r) * N + col] = f2bf(acc[m][n][r]);
      } else if (MODE == 1) {
        short* C = (short*)Cout;          // [N][M], row (=t) swizzled by dh&15
        float b = bias[col];
        s16x4 o;
#pragma unroll
        for (int r = 0; r < 4; ++r) o[r] = f2bf(acc[m][n][r] + b);
        int rowS = row ^ ((col & 15) << 3);
        *(s16x4*)(C + (size_t)col * M + rowS) = o;
      } else if (MODE == 2) {
        float* C = (float*)Cout;
        float b = bias[col];
#pragma unroll
        for (int r = 0; r < 4; ++r)
          C[(size_t)(row + r) * N + col] = acc[m][n][r] + b + resid[(size_t)(row + r) * N + col];
      } else {
        short* C = (short*)Cout;          // col-swizzled by row&7
#pragma unroll
        for (int r = 0; r < 4; ++r) {
          int rr = row + r;
          C[(size_t)rr * N + (col ^ ((rr & 7) << 3))] = f2bf(acc[m][n][r]);
        }
      }
    }
}

// ---------------- content bias: cb[h][t] = sum_d to[t,d]*WcbT[h,d] ----------------
__global__ void cb_kernel(const short* __restrict__ to_bf, const short* __restrict__ WcbT,
                          float* __restrict__ cbv) {
  __shared__ short Wl[16 * 1024];           // 32KB
  int tid = threadIdx.x;
  for (int i = tid; i < 2048; i += 256)
    ((s16x8*)Wl)[i] = ((const s16x8*)WcbT)[i];
  __syncthreads();
  int w = tid >> 6, l = tid & 63;
  int t = blockIdx.x * 4 + w;
  const s16x8* xr = (const s16x8*)(to_bf + ((size_t)t << 10) + l * 16);
  s16x8 x0 = xr[0], x1 = xr[1];
  float xf[16];
#pragma unroll
  for (int i = 0; i < 8; ++i) { xf[i] = bf2f(x0[i]); xf[8 + i] = bf2f(x1[i]); }
#pragma unroll
  for (int h = 0; h < 16; ++h) {
    const s16x8* wr_ = (const s16x8*)(Wl + h * 1024 + l * 16);
    s16x8 w0 = wr_[0], w1 = wr_[1];
    float acc = 0.f;
#pragma unroll
    for (int i = 0; i < 8; ++i) { acc += xf[i] * bf2f(w0[i]); acc += xf[8 + i] * bf2f(w1[i]); }
#pragma unroll
    for (int s = 32; s; s >>= 1) acc += __shfl_xor(acc, s);
    if (l == 0) cbv[(size_t)h * 2048 + t] = acc;
  }
}

// qmix_swz[h][f][d'] = q[f][d]*mix[h][d], d' = d ^ ((f&7)<<3)  (pre-swizzled for LDS staging)
__global__ void qmix_kernel(const short* __restrict__ q_bf, const short* __restrict__ mixbf,
                            short* __restrict__ qmix) {
  int f = blockIdx.x, h = blockIdx.y;
  int c = threadIdx.x * 8;
  s16x8 qv = *(const s16x8*)(q_bf + ((size_t)f << 10) + c);
  s16x8 mv = *(const s16x8*)(mixbf + ((size_t)h << 10) + c);
  s16x8 o;
#pragma unroll
  for (int i = 0; i < 8; ++i) o[i] = f2bf(bf2f(qv[i]) * bf2f(mv[i]));
  int cs = c ^ ((f & 7) << 3);
  *(s16x8*)(qmix + (((size_t)h * 2048 + f) << 10) + cs) = o;
}

// ---------------- flash attention v2: block = (128 f-rows, head), 4 waves, swizzled LDS --------
// LDS map (56KB): qm[128][64] @0 | kt[128][64] @16K | vt[64][128] @32K | cbl[2048]f32 @48K
// pt overlay (per-wave [32][128], 256B rows) on qm+kt region during PV phase.
template <bool QMIX>
__global__ __launch_bounds__(256, 2)
void attn_kernel(const short* __restrict__ qsrc, const short* __restrict__ k_swz,
                 const short* __restrict__ vT_swz, const short* __restrict__ mixbf,
                 const float* __restrict__ cbg, short* __restrict__ ctx_bf) {
  __shared__ __align__(16) char smem[57344];
  float* cbl = (float*)(smem + 49152);
  int f0 = blockIdx.x * 128, h = blockIdx.y;
  int tid = threadIdx.x, w = tid >> 6, l = tid & 63;
  int lr = l >> 4, lc = l & 15;
  for (int i = tid; i < 512; i += 256)
    ((f32x4*)cbl)[i] = ((const f32x4*)(cbg + (size_t)h * 2048))[i];
  float m_run[8], l_run[8];
#pragma unroll
  for (int s2 = 0; s2 < 8; ++s2) { m_run[s2] = -1e30f; l_run[s2] = 0.f; }
  f32x4 ctx[2][4] = {};
  const short* qbase = QMIX ? qsrc + (((size_t)h * 2048 + f0) << 10)
                            : qsrc + ((size_t)f0 << 10);

  for (int t0 = 0; t0 < 2048; t0 += 128) {
    f32x4 sacc[2][8] = {};
    for (int k0 = 0; k0 < 1024; k0 += 64) {
      __syncthreads();
      if (QMIX) {
#pragma unroll
        for (int i = 0; i < 4; ++i) {
          int off = i * 4096 + tid * 16;
          int r = off >> 7, c = off & 127;
          g2l16(qbase + ((size_t)r << 10) + k0 + (c >> 1), smem + off);
        }
      } else {
#pragma unroll
        for (int i = 0; i < 4; ++i) {
          int off = i * 4096 + tid * 16;
          int r = off >> 7, c = off & 127;
          s16x8 qv = *(const s16x8*)(qbase + ((size_t)r << 10) + k0 + (c >> 1));
          s16x8 mv = *(const s16x8*)(mixbf + ((size_t)h << 10) + k0 + (c >> 1));
          s16x8 o;
#pragma unroll
          for (int e = 0; e < 8; ++e) o[e] = f2bf(bf2f(qv[e]) * bf2f(mv[e]));
          *(s16x8*)(smem + (r << 7) + (c ^ ((r & 7) << 4))) = o;
        }
      }
#pragma unroll
      for (int i = 0; i < 4; ++i) {
        int off = i * 4096 + tid * 16;
        int r = off >> 7, c = off & 127;
        g2l16(k_swz + ((size_t)(t0 + r) << 10) + k0 + (c >> 1), smem + 16384 + off);
      }
      if (k0 == 0) {
#pragma unroll
        for (int i = 0; i < 4; ++i) {
          int off = i * 4096 + tid * 16;
          int r = off >> 8, c = off & 255;
          g2l16(vT_swz + ((size_t)(h * 64 + r) << 11) + t0 + (c >> 1), smem + 32768 + off);
        }
      }
      __syncthreads();
#pragma unroll
      for (int ks = 0; ks < 2; ++ks) {
        s16x8 af[2], bfr[8];
#pragma unroll
        for (int m = 0; m < 2; ++m) {
          int row = w * 32 + m * 16 + lc;
          af[m] = *(const s16x8*)(smem + (row << 7) + ((ks * 64 + lr * 16) ^ ((row & 7) << 4)));
        }
#pragma unroll
        for (int n = 0; n < 8; ++n) {
          int row = n * 16 + lc;
          bfr[n] = *(const s16x8*)(smem + 16384 + (row << 7) + ((ks * 64 + lr * 16) ^ ((row & 7) << 4)));
        }
#pragma unroll
        for (int m = 0; m < 2; ++m)
#pragma unroll
          for (int n = 0; n < 8; ++n)
            sacc[m][n] = __builtin_amdgcn_mfma_f32_16x16x32_bf16(af[m], bfr[n], sacc[m][n], 0, 0, 0);
      }
    }
    // ---- online softmax (reg-only; slot s2 = m*4+r owns f-row w*32+m*16+lr*4+r)
    float pm[8];
#pragma unroll
    for (int s2 = 0; s2 < 8; ++s2) pm[s2] = -1e30f;
#pragma unroll
    for (int m = 0; m < 2; ++m)
#pragma unroll
      for (int n = 0; n < 8; ++n) {
        float cbv = cbl[t0 + n * 16 + lc];
#pragma unroll
        for (int r = 0; r < 4; ++r) {
          float s = (sacc[m][n][r] + cbv) * 0.125f;
          sacc[m][n][r] = s;
          pm[m * 4 + r] = fmaxf(pm[m * 4 + r], s);
        }
      }
#pragma unroll
    for (int s_ = 1; s_ < 16; s_ <<= 1)
#pragma unroll
      for (int s2 = 0; s2 < 8; ++s2) pm[s2] = fmaxf(pm[s2], __shfl_xor(pm[s2], s_));
    float ts[8];
#pragma unroll
    for (int s2 = 0; s2 < 8; ++s2) {
      float mnew = fmaxf(m_run[s2], pm[s2]);
      float corr = __expf(m_run[s2] - mnew);
      m_run[s2] = mnew; l_run[s2] *= corr; ts[s2] = 0.f;
      int m = s2 >> 2, r = s2 & 3;
#pragma unroll
      for (int n2 = 0; n2 < 4; ++n2) ctx[m][n2][r] *= corr;
    }
#pragma unroll
    for (int m = 0; m < 2; ++m)
#pragma unroll
      for (int n = 0; n < 8; ++n)
#pragma unroll
        for (int r = 0; r < 4; ++r) {
          float e = __expf(sacc[m][n][r] - m_run[m * 4 + r]);
          sacc[m][n][r] = e;
          ts[m * 4 + r] += e;
        }
#pragma unroll
    for (int s_ = 1; s_ < 16; s_ <<= 1)
#pragma unroll
      for (int s2 = 0; s2 < 8; ++s2) ts[s2] += __shfl_xor(ts[s2], s_);
#pragma unroll
    for (int s2 = 0; s2 < 8; ++s2) l_run[s2] += ts[s2];
    __syncthreads();                       // all waves done reading qm/kt -> pt overlay safe
    // ---- P -> per-wave swizzled LDS (overlay on qm/kt)
    char* ptw = smem + w * 8192;
#pragma unroll
    for (int m = 0; m < 2; ++m)
#pragma unroll
      for (int n = 0; n < 8; ++n)
#pragma unroll
        for (int r = 0; r < 4; ++r) {
          int row = m * 16 + lr * 4 + r;
          int x = (n * 32 + lc * 2) ^ ((row & 15) << 4);
          *(short*)(ptw + (row << 8) + x) = f2bf(sacc[m][n][r]);
        }
    // ---- PV
#pragma unroll
    for (int ks = 0; ks < 4; ++ks) {
      s16x8 paf[2], vbf[4];
#pragma unroll
      for (int m = 0; m < 2; ++m) {
        int row = m * 16 + lc;
        paf[m] = *(const s16x8*)(ptw + (row << 8) + ((ks * 64 + lr * 16) ^ ((row & 15) << 4)));
      }
#pragma unroll
      for (int n2 = 0; n2 < 4; ++n2) {
        int row = n2 * 16 + lc;
        vbf[n2] = *(const s16x8*)(smem + 32768 + (row << 8) + ((ks * 64 + lr * 16) ^ ((row & 15) << 4)));
      }
#pragma unroll
      for (int m = 0; m < 2; ++m)
#pragma unroll
        for (int n2 = 0; n2 < 4; ++n2)
          ctx[m][n2] = __builtin_amdgcn_mfma_f32_16x16x32_bf16(paf[m], vbf[n2], ctx[m][n2], 0, 0, 0);
    }
  }
#pragma unroll
  for (int m = 0; m < 2; ++m)
#pragma unroll
    for (int n2 = 0; n2 < 4; ++n2)
#pragma unroll
      for (int r = 0; r < 4; ++r) {
        float o = ctx[m][n2][r] / l_run[m * 4 + r];
        ctx_bf[(size_t)(f0 + w * 32 + m * 16 + lr * 4 + r) * 1024 + h * 64 + n2 * 16 + lc] = f2bf(o);
      }
}

// ---------------- LayerNorm (in-place on d_out) ----------------
__global__ void ln_kernel(const float* __restrict__ res, const float* __restrict__ gamma,
                          const float* __restrict__ beta, float* __restrict__ out) {
  int row = blockIdx.x, tid = threadIdx.x;
  f32x4 x = *(const f32x4*)(res + ((size_t)row << 10) + tid * 4);
  float s = x[0] + x[1] + x[2] + x[3];
  float s2 = x[0] * x[0] + x[1] * x[1] + x[2] * x[2] + x[3] * x[3];
#pragma unroll
  for (int m = 1; m < 64; m <<= 1) { s += __shfl_xor(s, m); s2 += __shfl_xor(s2, m); }
  __shared__ float red[8];
  int w = tid >> 6, l = tid & 63;
  if (l == 0) { red[w] = s; red[4 + w] = s2; }
  __syncthreads();
  s = red[0] + red[1] + red[2] + red[3];
  s2 = red[4] + red[5] + red[6] + red[7];
  float mu = s * (1.f / 1024.f);
  float var = s2 * (1.f / 1024.f) - mu * mu;
  float rstd = rsqrtf(var + 1e-5f);
  f32x4 o;
#pragma unroll
  for (int i = 0; i < 4; ++i)
    o[i] = (x[i] - mu) * rstd * gamma[tid * 4 + i] + beta[tid * 4 + i];
  *(f32x4*)(out + ((size_t)row << 10) + tid * 4) = o;
}

// ---------------- launch ----------------
extern "C" void kernel_launch(void* const* d_in, const int* in_sizes, int n_in,
                              void* d_out, int out_size, void* d_ws, size_t ws_size,
                              hipStream_t stream) {
  const float* hidden = (const float*)d_in[0];
  const int*   fpos   = (const int*)d_in[1];
  const int*   tpos   = (const int*)d_in[2];
  const float* Wq     = (const float*)d_in[3];
  const float* Wk     = (const float*)d_in[4];
  const float* Wcb    = (const float*)d_in[5];
  const float* Wv     = (const float*)d_in[6];
  const float* bv     = (const float*)d_in[7];
  const float* mixing = (const float*)d_in[8];
  const float* Wd     = (const float*)d_in[9];
  const float* bd     = (const float*)d_in[10];
  const float* gamma  = (const float*)d_in[11];
  const float* beta   = (const float*)d_in[12];

  char* p = (char*)d_ws;
  auto alloc = [&](size_t bytes) { char* r = p; p += (bytes + 255) & ~(size_t)255; return r; };
  float* from_f  = (float*)alloc((size_t)2048 * 1024 * 4);
  short* from_bf = (short*)alloc((size_t)2048 * 1024 * 2);
  short* to_bf   = (short*)alloc((size_t)2048 * 1024 * 2);
  short* WqT     = (short*)alloc((size_t)1024 * 1024 * 2);
  short* WkT     = (short*)alloc((size_t)1024 * 1024 * 2);
  short* WvT     = (short*)alloc((size_t)1024 * 1024 * 2);
  short* WdT     = (short*)alloc((size_t)1024 * 1024 * 2);
  short* WcbT    = (short*)alloc((size_t)16 * 1024 * 2);
  short* mixbf   = (short*)alloc((size_t)16 * 1024 * 2);
  short* q_bf    = (short*)alloc((size_t)2048 * 1024 * 2);
  short* k_swz   = (short*)alloc((size_t)2048 * 1024 * 2);
  short* vTs     = (short*)alloc((size_t)1024 * 2048 * 2);
  float* cbb     = (float*)alloc((size_t)16 * 2048 * 4);
  short* ctx_bf  = (short*)alloc((size_t)2048 * 1024 * 2);
  size_t used = (size_t)(p - (char*)d_ws);
  short* qmixb = (short*)p;
  bool use_qmix = ws_size >= used + (size_t)16 * 2048 * 1024 * 2;

  wtrans_kernel<<<dim3(16, 16, 4), 256, 0, stream>>>(Wq, Wk, Wv, Wd, WqT, WkT, WvT, WdT);
  smallconv_kernel<<<128, 256, 0, stream>>>(Wcb, mixing, WcbT, mixbf);
  gather_kernel<<<dim3(2048, 2), 256, 0, stream>>>(hidden, fpos, tpos, from_f, from_bf, to_bf);
  gemm_bt<0><<<dim3(16, 8), 256, 0, stream>>>(from_bf, WqT, nullptr, nullptr, q_bf, 2048, 1024);
  gemm_bt<3><<<dim3(16, 8), 256, 0, stream>>>(to_bf, WkT, nullptr, nullptr, k_swz, 2048, 1024);
  gemm_bt<1><<<dim3(16, 8), 256, 0, stream>>>(to_bf, WvT, bv, nullptr, vTs, 2048, 1024);
  cb_kernel<<<512, 256, 0, stream>>>(to_bf, WcbT, cbb);
  if (use_qmix) {
    qmix_kernel<<<dim3(2048, 16), 128, 0, stream>>>(q_bf, mixbf, qmixb);
    attn_kernel<true><<<dim3(16, 16), 256, 0, stream>>>(qmixb, k_swz, vTs, mixbf, cbb, ctx_bf);
  } else {
    attn_kernel<false><<<dim3(16, 16), 256, 0, stream>>>(q_bf, k_swz, vTs, mixbf, cbb, ctx_bf);
  }
  gemm_bt<2><<<dim3(16, 8), 256, 0, stream>>>(ctx_bf, WdT, bd, from_f, (float*)d_out, 2048, 1024);
  ln_kernel<<<2048, 256, 0, stream>>>((float*)d_out, gamma, beta, (float*)d_out);
}

// Round 3
// 542.707 us; speedup vs baseline: 1.1593x; 1.0341x over previous
//
#include <hip/hip_runtime.h>
#include <stdint.h>

// ---------------- types & helpers ----------------
typedef float  f32x4 __attribute__((ext_vector_type(4)));
typedef short  s16x8 __attribute__((ext_vector_type(8)));
typedef short  s16x4 __attribute__((ext_vector_type(4)));

__device__ __forceinline__ float bf2f(short s) {
  unsigned u = ((unsigned)(unsigned short)s) << 16;
  return __builtin_bit_cast(float, u);
}
__device__ __forceinline__ short f2bf(float f) {
  unsigned u = __builtin_bit_cast(unsigned, f);
  u = u + 0x7fffu + ((u >> 16) & 1u);   // RNE
  return (short)(u >> 16);
}
__device__ __forceinline__ void g2l16(const void* g, void* l) {
  __builtin_amdgcn_global_load_lds((const __attribute__((address_space(1))) void*)g,
                                   (__attribute__((address_space(3))) void*)l,
                                   16, 0, 0);
}
#define BARRIER() do { __builtin_amdgcn_s_barrier(); __builtin_amdgcn_sched_barrier(0); } while (0)
#define VMCNT(N)  asm volatile("s_waitcnt vmcnt(" #N ")" ::: "memory")

// ---------------- prep: transpose 1024x1024 f32 weights -> bf16 [N][K] ----------------
__global__ void wtrans_kernel(const float* __restrict__ Wq, const float* __restrict__ Wk,
                              const float* __restrict__ Wv, const float* __restrict__ Wd,
                              short* __restrict__ WqT, short* __restrict__ WkT,
                              short* __restrict__ WvT, short* __restrict__ WdT) {
  __shared__ float tile[64][65];
  const float* src; short* dst;
  switch (blockIdx.z) {
    case 0: src = Wq; dst = WqT; break;
    case 1: src = Wk; dst = WkT; break;
    case 2: src = Wv; dst = WvT; break;
    default: src = Wd; dst = WdT; break;
  }
  int k0 = blockIdx.y * 64;
  int n0 = blockIdx.x * 64;
  int tid = threadIdx.x;
#pragma unroll
  for (int p = 0; p < 4; ++p) {
    int idx = p * 1024 + tid * 4;
    int r = idx >> 6, c = idx & 63;
    f32x4 v = *(const f32x4*)(src + (size_t)(k0 + r) * 1024 + n0 + c);
    tile[r][c + 0] = v[0]; tile[r][c + 1] = v[1];
    tile[r][c + 2] = v[2]; tile[r][c + 3] = v[3];
  }
  __syncthreads();
#pragma unroll
  for (int p = 0; p < 2; ++p) {
    int idx = p * 2048 + tid * 8;
    int r = idx >> 6, c = idx & 63;
    s16x8 o;
#pragma unroll
    for (int i = 0; i < 8; ++i) o[i] = f2bf(tile[c + i][r]);
    *(s16x8*)(dst + (size_t)(n0 + r) * 1024 + k0 + c) = o;
  }
}

__global__ void smallconv_kernel(const float* __restrict__ Wcb, const float* __restrict__ mixing,
                                 short* __restrict__ WcbT, short* __restrict__ mixbf) {
  int idx = blockIdx.x * 256 + threadIdx.x;
  if (idx < 16384) {
    int h = idx >> 10, d = idx & 1023;
    WcbT[idx] = f2bf(Wcb[d * 16 + h]);
  } else {
    int j = idx - 16384;
    mixbf[j] = f2bf(mixing[j]);
  }
}

__global__ void gather_kernel(const float* __restrict__ hidden, const int* __restrict__ fpos,
                              const int* __restrict__ tpos, float* __restrict__ from_f,
                              short* __restrict__ from_bf, short* __restrict__ to_bf) {
  int row = blockIdx.x;
  int c = threadIdx.x * 4;
  if (blockIdx.y == 0) {
    int src = fpos[row] & 511;
    f32x4 v = *(const f32x4*)(hidden + (size_t)src * 1024 + c);
    *(f32x4*)(from_f + (size_t)row * 1024 + c) = v;
    s16x4 o;
#pragma unroll
    for (int i = 0; i < 4; ++i) o[i] = f2bf(v[i]);
    *(s16x4*)(from_bf + (size_t)row * 1024 + c) = o;
  } else {
    int src = tpos[row] & 511;
    f32x4 v = *(const f32x4*)(hidden + (size_t)src * 1024 + c);
    s16x4 o;
#pragma unroll
    for (int i = 0; i < 4; ++i) o[i] = f2bf(v[i]);
    *(s16x4*)(to_bf + (size_t)row * 1024 + c) = o;
  }
}

// ---------------- merged QKV GEMM (z: 0=q plain, 1=k col-swizzled, 2=v transposed/swz) -------
__global__ __launch_bounds__(256, 2)
void qkv_gemm(const short* __restrict__ from_bf, const short* __restrict__ to_bf,
              const short* __restrict__ WqT, const short* __restrict__ WkT,
              const short* __restrict__ WvT, const float* __restrict__ bv,
              short* __restrict__ q_bf, short* __restrict__ k_swz, short* __restrict__ vTs) {
  __shared__ __align__(16) short As[128][64];
  __shared__ __align__(16) short Bs[128][64];
  int mode = blockIdx.z;
  const short* A = (mode == 0) ? from_bf : to_bf;
  const short* B = (mode == 0) ? WqT : (mode == 1) ? WkT : WvT;
  int m0 = blockIdx.x * 128, n0 = blockIdx.y * 128;
  int tid = threadIdx.x;
  int w = tid >> 6, l = tid & 63;
  int wr = w >> 1, wc = w & 1;
  f32x4 acc[4][4] = {};
  for (int k0 = 0; k0 < 1024; k0 += 64) {
    __syncthreads();
#pragma unroll
    for (int i = 0; i < 4; ++i) {
      int off = i * 4096 + tid * 16;
      int r = off >> 7, cb_ = off & 127;
      g2l16(A + ((size_t)(m0 + r) << 10) + k0 + (cb_ >> 1), (short*)As + (off >> 1));
      g2l16(B + ((size_t)(n0 + r) << 10) + k0 + (cb_ >> 1), (short*)Bs + (off >> 1));
    }
    __syncthreads();
#pragma unroll
    for (int ks = 0; ks < 2; ++ks) {
      s16x8 af[4], bfr[4];
#pragma unroll
      for (int m = 0; m < 4; ++m)
        af[m] = *(const s16x8*)&As[wr * 64 + m * 16 + (l & 15)][ks * 32 + (l >> 4) * 8];
#pragma unroll
      for (int n = 0; n < 4; ++n)
        bfr[n] = *(const s16x8*)&Bs[wc * 64 + n * 16 + (l & 15)][ks * 32 + (l >> 4) * 8];
#pragma unroll
      for (int m = 0; m < 4; ++m)
#pragma unroll
        for (int n = 0; n < 4; ++n)
          acc[m][n] = __builtin_amdgcn_mfma_f32_16x16x32_bf16(af[m], bfr[n], acc[m][n], 0, 0, 0);
    }
  }
  int lr = (l >> 4) * 4, lc = l & 15;
#pragma unroll
  for (int m = 0; m < 4; ++m)
#pragma unroll
    for (int n = 0; n < 4; ++n) {
      int row = m0 + wr * 64 + m * 16 + lr;
      int col = n0 + wc * 64 + n * 16 + lc;
      if (mode == 0) {
#pragma unroll
        for (int r = 0; r < 4; ++r) q_bf[(size_t)(row + r) * 1024 + col] = f2bf(acc[m][n][r]);
      } else if (mode == 1) {
#pragma unroll
        for (int r = 0; r < 4; ++r) {
          int rr = row + r;
          k_swz[(size_t)rr * 1024 + (col ^ ((rr & 7) << 3))] = f2bf(acc[m][n][r]);
        }
      } else {
        float b = bv[col];
        s16x4 o;
#pragma unroll
        for (int r = 0; r < 4; ++r) o[r] = f2bf(acc[m][n][r] + b);
        int tsw = (row & ~255) | ((row & 255) ^ ((col & 15) << 3));
        *(s16x4*)(vTs + (size_t)col * 2048 + tsw) = o;
      }
    }
}

// ---------------- final GEMM: C f32 = ctx @ WdT + bd + resid ----------------
__global__ __launch_bounds__(256, 2)
void gemm_out(const short* __restrict__ A, const short* __restrict__ B,
              const float* __restrict__ bias, const float* __restrict__ resid,
              float* __restrict__ Cout) {
  __shared__ __align__(16) short As[128][64];
  __shared__ __align__(16) short Bs[128][64];
  int m0 = blockIdx.x * 128, n0 = blockIdx.y * 128;
  int tid = threadIdx.x;
  int w = tid >> 6, l = tid & 63;
  int wr = w >> 1, wc = w & 1;
  f32x4 acc[4][4] = {};
  for (int k0 = 0; k0 < 1024; k0 += 64) {
    __syncthreads();
#pragma unroll
    for (int i = 0; i < 4; ++i) {
      int off = i * 4096 + tid * 16;
      int r = off >> 7, cb_ = off & 127;
      g2l16(A + ((size_t)(m0 + r) << 10) + k0 + (cb_ >> 1), (short*)As + (off >> 1));
      g2l16(B + ((size_t)(n0 + r) << 10) + k0 + (cb_ >> 1), (short*)Bs + (off >> 1));
    }
    __syncthreads();
#pragma unroll
    for (int ks = 0; ks < 2; ++ks) {
      s16x8 af[4], bfr[4];
#pragma unroll
      for (int m = 0; m < 4; ++m)
        af[m] = *(const s16x8*)&As[wr * 64 + m * 16 + (l & 15)][ks * 32 + (l >> 4) * 8];
#pragma unroll
      for (int n = 0; n < 4; ++n)
        bfr[n] = *(const s16x8*)&Bs[wc * 64 + n * 16 + (l & 15)][ks * 32 + (l >> 4) * 8];
#pragma unroll
      for (int m = 0; m < 4; ++m)
#pragma unroll
        for (int n = 0; n < 4; ++n)
          acc[m][n] = __builtin_amdgcn_mfma_f32_16x16x32_bf16(af[m], bfr[n], acc[m][n], 0, 0, 0);
    }
  }
  int lr = (l >> 4) * 4, lc = l & 15;
#pragma unroll
  for (int m = 0; m < 4; ++m)
#pragma unroll
    for (int n = 0; n < 4; ++n) {
      int row = m0 + wr * 64 + m * 16 + lr;
      int col = n0 + wc * 64 + n * 16 + lc;
      float b = bias[col];
#pragma unroll
      for (int r = 0; r < 4; ++r)
        Cout[(size_t)(row + r) * 1024 + col] = acc[m][n][r] + b + resid[(size_t)(row + r) * 1024 + col];
    }
}

// ---------------- content bias ----------------
__global__ void cb_kernel(const short* __restrict__ to_bf, const short* __restrict__ WcbT,
                          float* __restrict__ cbv) {
  __shared__ short Wl[16 * 1024];
  int tid = threadIdx.x;
  for (int i = tid; i < 2048; i += 256)
    ((s16x8*)Wl)[i] = ((const s16x8*)WcbT)[i];
  __syncthreads();
  int w = tid >> 6, l = tid & 63;
  int t = blockIdx.x * 4 + w;
  const s16x8* xr = (const s16x8*)(to_bf + ((size_t)t << 10) + l * 16);
  s16x8 x0 = xr[0], x1 = xr[1];
  float xf[16];
#pragma unroll
  for (int i = 0; i < 8; ++i) { xf[i] = bf2f(x0[i]); xf[8 + i] = bf2f(x1[i]); }
#pragma unroll
  for (int h = 0; h < 16; ++h) {
    const s16x8* wr_ = (const s16x8*)(Wl + h * 1024 + l * 16);
    s16x8 w0 = wr_[0], w1 = wr_[1];
    float acc = 0.f;
#pragma unroll
    for (int i = 0; i < 8; ++i) { acc += xf[i] * bf2f(w0[i]); acc += xf[8 + i] * bf2f(w1[i]); }
#pragma unroll
    for (int s = 32; s; s >>= 1) acc += __shfl_xor(acc, s);
    if (l == 0) cbv[(size_t)h * 2048 + t] = acc;
  }
}

// qmix_swz[h][f][d'] = q[f][d]*mix[h][d], d' = d ^ ((f&7)<<3)
__global__ void qmix_kernel(const short* __restrict__ q_bf, const short* __restrict__ mixbf,
                            short* __restrict__ qmix) {
  int f = blockIdx.x, h = blockIdx.y;
  int c = threadIdx.x * 8;
  s16x8 qv = *(const s16x8*)(q_bf + ((size_t)f << 10) + c);
  s16x8 mv = *(const s16x8*)(mixbf + ((size_t)h << 10) + c);
  s16x8 o;
#pragma unroll
  for (int i = 0; i < 8; ++i) o[i] = f2bf(bf2f(qv[i]) * bf2f(mv[i]));
  int cs = c ^ ((f & 7) << 3);
  *(s16x8*)(qmix + (((size_t)h * 2048 + f) << 10) + cs) = o;
}

// ---------------- flash attention v3: pipelined, TBLK=256, dbuf chunks ----------------
// LDS (136KB): qmA@0(16K) qmB@16K ktA@32K(32K) ktB@64K(32K) vt@96K(32K) cbl@128K(8K)
// pt (per-wave [32][256B-rows x128]) overlays ktB during PV.
__device__ __forceinline__ void issue_chunk(const short* qbase, const short* ksrc, int t0,
                                            int kk0, char* qmb, char* ktb, int tid) {
#pragma unroll
  for (int i = 0; i < 4; ++i) {
    int off = i * 4096 + tid * 16;
    int r = off >> 7, co = off & 127;
    g2l16(qbase + ((size_t)r << 10) + kk0 + (co >> 1), qmb + off);
  }
#pragma unroll
  for (int i = 0; i < 8; ++i) {
    int off = i * 4096 + tid * 16;
    int r = off >> 7, co = off & 127;
    g2l16(ksrc + ((size_t)(t0 + r) << 10) + kk0 + (co >> 1), ktb + off);
  }
}
__device__ __forceinline__ void issue_kt(const short* ksrc, int t0, int kk0, char* ktb, int tid) {
#pragma unroll
  for (int i = 0; i < 8; ++i) {
    int off = i * 4096 + tid * 16;
    int r = off >> 7, co = off & 127;
    g2l16(ksrc + ((size_t)(t0 + r) << 10) + kk0 + (co >> 1), ktb + off);
  }
}
__device__ __forceinline__ void issue_vt(const short* vsrc, int h, int t0, char* vtb, int tid) {
#pragma unroll
  for (int i = 0; i < 8; ++i) {
    int off = i * 4096 + tid * 16;
    int r = off >> 9, co = off & 511;
    g2l16(vsrc + ((size_t)(h * 64 + r) << 11) + t0 + (co >> 1), vtb + off);
  }
}
__device__ __forceinline__ void stage_qm_sync(const short* qb, const short* mixh, int kk0,
                                              char* qmb, int tid) {
#pragma unroll
  for (int i = 0; i < 4; ++i) {
    int off = i * 4096 + tid * 16;
    int r = off >> 7, co = off & 127;
    s16x8 qv = *(const s16x8*)(qb + ((size_t)r << 10) + kk0 + (co >> 1));
    s16x8 mv = *(const s16x8*)(mixh + kk0 + (co >> 1));
    s16x8 o;
#pragma unroll
    for (int e = 0; e < 8; ++e) o[e] = f2bf(bf2f(qv[e]) * bf2f(mv[e]));
    *(s16x8*)(qmb + (r << 7) + (co ^ ((r & 7) << 4))) = o;
  }
}
__device__ __forceinline__ void qk_compute(const char* qmb, const char* ktb,
                                           f32x4 (&sacc)[2][16], int w, int lr, int lc) {
#pragma unroll
  for (int ks = 0; ks < 2; ++ks) {
    int xr = (ks * 64 + lr * 16) ^ ((lc & 7) << 4);
    s16x8 af[2];
#pragma unroll
    for (int m = 0; m < 2; ++m)
      af[m] = *(const s16x8*)(qmb + ((w * 32 + m * 16 + lc) << 7) + xr);
#pragma unroll
    for (int n = 0; n < 16; ++n) {
      s16x8 bfr = *(const s16x8*)(ktb + ((n * 16 + lc) << 7) + xr);
      sacc[0][n] = __builtin_amdgcn_mfma_f32_16x16x32_bf16(af[0], bfr, sacc[0][n], 0, 0, 0);
      sacc[1][n] = __builtin_amdgcn_mfma_f32_16x16x32_bf16(af[1], bfr, sacc[1][n], 0, 0, 0);
    }
  }
}

template <bool QMIX>
__global__ __launch_bounds__(256, 1)
void attn_kernel(const short* __restrict__ qsrc, const short* __restrict__ k_swz,
                 const short* __restrict__ vTs, const short* __restrict__ mixbf,
                 const float* __restrict__ cbg, short* __restrict__ ctx_bf) {
  __shared__ __align__(16) char smem[139264];
  char* qmA = smem;            char* qmB = smem + 16384;
  char* ktA = smem + 32768;    char* ktB = smem + 65536;
  char* vt  = smem + 98304;    float* cbl = (float*)(smem + 131072);
  int f0 = blockIdx.x * 128, h = blockIdx.y;
  int tid = threadIdx.x, w = tid >> 6, l = tid & 63;
  int lr = l >> 4, lc = l & 15;
  const short* qbase = QMIX ? qsrc + (((size_t)h * 2048 + f0) << 10)
                            : qsrc + ((size_t)f0 << 10);
  const short* mixh = mixbf + ((size_t)h << 10);

  if (QMIX) {
#pragma unroll
    for (int i = 0; i < 2; ++i)
      g2l16((const char*)cbg + h * 8192 + i * 4096 + tid * 16, smem + 131072 + i * 4096 + tid * 16);
    issue_chunk(qbase, k_swz, 0, 0, qmA, ktA, tid);
    issue_vt(vTs, h, 0, vt, tid);
  } else {
    for (int i = tid; i < 2048; i += 256) cbl[i] = cbg[(size_t)h * 2048 + i];
  }

  float m_run[8], l_run[8];
#pragma unroll
  for (int s2 = 0; s2 < 8; ++s2) { m_run[s2] = -1e30f; l_run[s2] = 0.f; }
  f32x4 ctx[2][4] = {};

  for (int t0 = 0; t0 < 2048; t0 += 256) {
    if (QMIX) { if (t0 > 0) issue_vt(vTs, h, t0, vt, tid); }
    else      { issue_vt(vTs, h, t0, vt, tid); }
    f32x4 sacc[2][16] = {};
#pragma unroll
    for (int c = 0; c < 16; ++c) {
      char* qmb = (c & 1) ? qmB : qmA;
      char* ktb = (c & 1) ? ktB : ktA;
      if (QMIX) {
        if (c < 15) issue_chunk(qbase, k_swz, t0, (c + 1) * 64,
                                (c & 1) ? qmA : qmB, (c & 1) ? ktA : ktB, tid);
        else if (t0 < 1792) issue_chunk(qbase, k_swz, t0 + 256, 0, qmA, ktA, tid);
        if (c == 0) { VMCNT(20); }
        else if (c == 15) { if (t0 == 1792) { VMCNT(0); } else { VMCNT(12); } }
        else { VMCNT(12); }
        BARRIER();
      } else {
        stage_qm_sync(qbase, mixh, c * 64, qmb, tid);
        issue_kt(k_swz, t0, c * 64, ktb, tid);
        __syncthreads();
      }
      qk_compute(qmb, ktb, sacc, w, lr, lc);
      if (QMIX) { BARRIER(); } else { __syncthreads(); }
    }
    // ---- online softmax (reg-only; slot s2=m*4+r owns f-row w*32+m*16+lr*4+r)
    float pm[8];
#pragma unroll
    for (int s2 = 0; s2 < 8; ++s2) pm[s2] = -1e30f;
#pragma unroll
    for (int m = 0; m < 2; ++m)
#pragma unroll
      for (int n = 0; n < 16; ++n) {
        float cbv = cbl[t0 + n * 16 + lc];
#pragma unroll
        for (int r = 0; r < 4; ++r) {
          float s = (sacc[m][n][r] + cbv) * 0.125f;
          sacc[m][n][r] = s;
          pm[m * 4 + r] = fmaxf(pm[m * 4 + r], s);
        }
      }
#pragma unroll
    for (int s_ = 1; s_ < 16; s_ <<= 1)
#pragma unroll
      for (int s2 = 0; s2 < 8; ++s2) pm[s2] = fmaxf(pm[s2], __shfl_xor(pm[s2], s_));
    float ts[8];
#pragma unroll
    for (int s2 = 0; s2 < 8; ++s2) {
      float mnew = fmaxf(m_run[s2], pm[s2]);
      float corr = __expf(m_run[s2] - mnew);
      m_run[s2] = mnew; l_run[s2] *= corr; ts[s2] = 0.f;
      int m = s2 >> 2, r = s2 & 3;
#pragma unroll
      for (int n2 = 0; n2 < 4; ++n2) ctx[m][n2][r] *= corr;
    }
#pragma unroll
    for (int m = 0; m < 2; ++m)
#pragma unroll
      for (int n = 0; n < 16; ++n)
#pragma unroll
        for (int r = 0; r < 4; ++r) {
          float e = __expf(sacc[m][n][r] - m_run[m * 4 + r]);
          sacc[m][n][r] = e;
          ts[m * 4 + r] += e;
        }
#pragma unroll
    for (int s_ = 1; s_ < 16; s_ <<= 1)
#pragma unroll
      for (int s2 = 0; s2 < 8; ++s2) ts[s2] += __shfl_xor(ts[s2], s_);
#pragma unroll
    for (int s2 = 0; s2 < 8; ++s2) l_run[s2] += ts[s2];
    // ---- P -> per-wave swizzled LDS (overlay on ktB; c15 read ktB, barrier passed)
    char* ptw = ktB + w * 8192;
#pragma unroll
    for (int hh = 0; hh < 2; ++hh) {
#pragma unroll
      for (int m = 0; m < 2; ++m)
#pragma unroll
        for (int n = 0; n < 8; ++n) {
          int nn = hh * 8 + n;
#pragma unroll
          for (int r = 0; r < 4; ++r) {
            int row = m * 16 + lr * 4 + r;
            *(short*)(ptw + (row << 8) + ((n * 32 + lc * 2) ^ ((row & 15) << 4))) =
                f2bf(sacc[m][nn][r]);
          }
        }
#pragma unroll
      for (int ks = 0; ks < 4; ++ks) {
        s16x8 paf[2], vbf[4];
#pragma unroll
        for (int m = 0; m < 2; ++m) {
          int row = m * 16 + lc;
          paf[m] = *(const s16x8*)(ptw + (row << 8) + ((ks * 64 + lr * 16) ^ (lc << 4)));
        }
#pragma unroll
        for (int n2 = 0; n2 < 4; ++n2) {
          int row = n2 * 16 + lc;
          vbf[n2] = *(const s16x8*)(vt + (row << 9) + (((hh * 4 + ks) * 64 + lr * 16) ^ (lc << 4)));
        }
#pragma unroll
        for (int m = 0; m < 2; ++m)
#pragma unroll
          for (int n2 = 0; n2 < 4; ++n2)
            ctx[m][n2] = __builtin_amdgcn_mfma_f32_16x16x32_bf16(paf[m], vbf[n2], ctx[m][n2], 0, 0, 0);
      }
    }
    if (QMIX) { BARRIER(); } else { __syncthreads(); }
  }
#pragma unroll
  for (int m = 0; m < 2; ++m)
#pragma unroll
    for (int n2 = 0; n2 < 4; ++n2)
#pragma unroll
      for (int r = 0; r < 4; ++r) {
        float o = ctx[m][n2][r] / l_run[m * 4 + r];
        ctx_bf[(size_t)(f0 + w * 32 + m * 16 + lr * 4 + r) * 1024 + h * 64 + n2 * 16 + lc] = f2bf(o);
      }
}

// ---------------- LayerNorm (in-place) ----------------
__global__ void ln_kernel(const float* __restrict__ res, const float* __restrict__ gamma,
                          const float* __restrict__ beta, float* __restrict__ out) {
  int row = blockIdx.x, tid = threadIdx.x;
  f32x4 x = *(const f32x4*)(res + ((size_t)row << 10) + tid * 4);
  float s = x[0] + x[1] + x[2] + x[3];
  float s2 = x[0] * x[0] + x[1] * x[1] + x[2] * x[2] + x[3] * x[3];
#pragma unroll
  for (int m = 1; m < 64; m <<= 1) { s += __shfl_xor(s, m); s2 += __shfl_xor(s2, m); }
  __shared__ float red[8];
  int w = tid >> 6, l = tid & 63;
  if (l == 0) { red[w] = s; red[4 + w] = s2; }
  __syncthreads();
  s = red[0] + red[1] + red[2] + red[3];
  s2 = red[4] + red[5] + red[6] + red[7];
  float mu = s * (1.f / 1024.f);
  float var = s2 * (1.f / 1024.f) - mu * mu;
  float rstd = rsqrtf(var + 1e-5f);
  f32x4 o;
#pragma unroll
  for (int i = 0; i < 4; ++i)
    o[i] = (x[i] - mu) * rstd * gamma[tid * 4 + i] + beta[tid * 4 + i];
  *(f32x4*)(out + ((size_t)row << 10) + tid * 4) = o;
}

// ---------------- launch ----------------
extern "C" void kernel_launch(void* const* d_in, const int* in_sizes, int n_in,
                              void* d_out, int out_size, void* d_ws, size_t ws_size,
                              hipStream_t stream) {
  const float* hidden = (const float*)d_in[0];
  const int*   fpos   = (const int*)d_in[1];
  const int*   tpos   = (const int*)d_in[2];
  const float* Wq     = (const float*)d_in[3];
  const float* Wk     = (const float*)d_in[4];
  const float* Wcb    = (const float*)d_in[5];
  const float* Wv     = (const float*)d_in[6];
  const float* bv     = (const float*)d_in[7];
  const float* mixing = (const float*)d_in[8];
  const float* Wd     = (const float*)d_in[9];
  const float* bd     = (const float*)d_in[10];
  const float* gamma  = (const float*)d_in[11];
  const float* beta   = (const float*)d_in[12];

  char* p = (char*)d_ws;
  auto alloc = [&](size_t bytes) { char* r = p; p += (bytes + 255) & ~(size_t)255; return r; };
  float* from_f  = (float*)alloc((size_t)2048 * 1024 * 4);
  short* from_bf = (short*)alloc((size_t)2048 * 1024 * 2);
  short* to_bf   = (short*)alloc((size_t)2048 * 1024 * 2);
  short* WqT     = (short*)alloc((size_t)1024 * 1024 * 2);
  short* WkT     = (short*)alloc((size_t)1024 * 1024 * 2);
  short* WvT     = (short*)alloc((size_t)1024 * 1024 * 2);
  short* WdT     = (short*)alloc((size_t)1024 * 1024 * 2);
  short* WcbT    = (short*)alloc((size_t)16 * 1024 * 2);
  short* mixbf   = (short*)alloc((size_t)16 * 1024 * 2);
  short* q_bf    = (short*)alloc((size_t)2048 * 1024 * 2);
  short* k_swz   = (short*)alloc((size_t)2048 * 1024 * 2);
  short* vTs     = (short*)alloc((size_t)1024 * 2048 * 2);
  float* cbb     = (float*)alloc((size_t)16 * 2048 * 4);
  short* ctx_bf  = (short*)alloc((size_t)2048 * 1024 * 2);
  size_t used = (size_t)(p - (char*)d_ws);
  short* qmixb = (short*)p;
  bool use_qmix = ws_size >= used + (size_t)16 * 2048 * 1024 * 2;

  wtrans_kernel<<<dim3(16, 16, 4), 256, 0, stream>>>(Wq, Wk, Wv, Wd, WqT, WkT, WvT, WdT);
  smallconv_kernel<<<128, 256, 0, stream>>>(Wcb, mixing, WcbT, mixbf);
  gather_kernel<<<dim3(2048, 2), 256, 0, stream>>>(hidden, fpos, tpos, from_f, from_bf, to_bf);
  qkv_gemm<<<dim3(16, 8, 3), 256, 0, stream>>>(from_bf, to_bf, WqT, WkT, WvT, bv,
                                               q_bf, k_swz, vTs);
  cb_kernel<<<512, 256, 0, stream>>>(to_bf, WcbT, cbb);
  if (use_qmix) {
    qmix_kernel<<<dim3(2048, 16), 128, 0, stream>>>(q_bf, mixbf, qmixb);
    attn_kernel<true><<<dim3(16, 16), 256, 0, stream>>>(qmixb, k_swz, vTs, mixbf, cbb, ctx_bf);
  } else {
    attn_kernel<false><<<dim3(16, 16), 256, 0, stream>>>(q_bf, k_swz, vTs, mixbf, cbb, ctx_bf);
  }
  gemm_out<<<dim3(16, 8), 256, 0, stream>>>(ctx_bf, WdT, bd, from_f, (float*)d_out);
  ln_kernel<<<2048, 256, 0, stream>>>((float*)d_out, gamma, beta, (float*)d_out);
}

// Round 4
// 394.255 us; speedup vs baseline: 1.5958x; 1.3765x over previous
//
#include <hip/hip_runtime.h>
#include <stdint.h>

// ---------------- types & helpers ----------------
typedef float  f32x4 __attribute__((ext_vector_type(4)));
typedef float  f32x2 __attribute__((ext_vector_type(2)));
typedef short  s16x8 __attribute__((ext_vector_type(8)));
typedef short  s16x4 __attribute__((ext_vector_type(4)));

__device__ __forceinline__ float bf2f(short s) {
  unsigned u = ((unsigned)(unsigned short)s) << 16;
  return __builtin_bit_cast(float, u);
}
__device__ __forceinline__ short f2bf(float f) {
  unsigned u = __builtin_bit_cast(unsigned, f);
  u = u + 0x7fffu + ((u >> 16) & 1u);   // RNE
  return (short)(u >> 16);
}
__device__ __forceinline__ void g2l16(const void* g, void* l) {
  __builtin_amdgcn_global_load_lds((const __attribute__((address_space(1))) void*)g,
                                   (__attribute__((address_space(3))) void*)l,
                                   16, 0, 0);
}
#define BARRIER() do { __builtin_amdgcn_s_barrier(); __builtin_amdgcn_sched_barrier(0); } while (0)
#define VMCNT(N)  asm volatile("s_waitcnt vmcnt(" #N ")" ::: "memory")
#define MFMA(a, b, c) __builtin_amdgcn_mfma_f32_16x16x32_bf16(a, b, c, 0, 0, 0)

// ---------------- prep: transpose 1024x1024 f32 weights -> bf16 [N][K] ----------------
__global__ void wtrans_kernel(const float* __restrict__ Wq, const float* __restrict__ Wk,
                              const float* __restrict__ Wv, const float* __restrict__ Wd,
                              short* __restrict__ WqT, short* __restrict__ WkT,
                              short* __restrict__ WvT, short* __restrict__ WdT) {
  __shared__ float tile[64][65];
  const float* src; short* dst;
  switch (blockIdx.z) {
    case 0: src = Wq; dst = WqT; break;
    case 1: src = Wk; dst = WkT; break;
    case 2: src = Wv; dst = WvT; break;
    default: src = Wd; dst = WdT; break;
  }
  int k0 = blockIdx.y * 64;
  int n0 = blockIdx.x * 64;
  int tid = threadIdx.x;
#pragma unroll
  for (int p = 0; p < 4; ++p) {
    int idx = p * 1024 + tid * 4;
    int r = idx >> 6, c = idx & 63;
    f32x4 v = *(const f32x4*)(src + (size_t)(k0 + r) * 1024 + n0 + c);
    tile[r][c + 0] = v[0]; tile[r][c + 1] = v[1];
    tile[r][c + 2] = v[2]; tile[r][c + 3] = v[3];
  }
  __syncthreads();
#pragma unroll
  for (int p = 0; p < 2; ++p) {
    int idx = p * 2048 + tid * 8;
    int r = idx >> 6, c = idx & 63;
    s16x8 o;
#pragma unroll
    for (int i = 0; i < 8; ++i) o[i] = f2bf(tile[c + i][r]);
    *(s16x8*)(dst + (size_t)(n0 + r) * 1024 + k0 + c) = o;
  }
}

// Wcb [1024][16] -> WcbT bf16 [16][1024]; mixing [16][1024] -> bf16 (pre-scaled by 0.125)
__global__ void smallconv_kernel(const float* __restrict__ Wcb, const float* __restrict__ mixing,
                                 short* __restrict__ WcbT, short* __restrict__ mixbf) {
  int idx = blockIdx.x * 256 + threadIdx.x;
  if (idx < 16384) {
    int h = idx >> 10, d = idx & 1023;
    WcbT[idx] = f2bf(Wcb[d * 16 + h]);
  } else {
    int j = idx - 16384;
    mixbf[j] = f2bf(mixing[j] * 0.125f);
  }
}

__global__ void gather_kernel(const float* __restrict__ hidden, const int* __restrict__ fpos,
                              const int* __restrict__ tpos, float* __restrict__ from_f,
                              short* __restrict__ from_bf, short* __restrict__ to_bf) {
  int row = blockIdx.x;
  int c = threadIdx.x * 4;
  if (blockIdx.y == 0) {
    int src = fpos[row] & 511;
    f32x4 v = *(const f32x4*)(hidden + (size_t)src * 1024 + c);
    *(f32x4*)(from_f + (size_t)row * 1024 + c) = v;
    s16x4 o;
#pragma unroll
    for (int i = 0; i < 4; ++i) o[i] = f2bf(v[i]);
    *(s16x4*)(from_bf + (size_t)row * 1024 + c) = o;
  } else {
    int src = tpos[row] & 511;
    f32x4 v = *(const f32x4*)(hidden + (size_t)src * 1024 + c);
    s16x4 o;
#pragma unroll
    for (int i = 0; i < 4; ++i) o[i] = f2bf(v[i]);
    *(s16x4*)(to_bf + (size_t)row * 1024 + c) = o;
  }
}

// ---------------- merged QKV GEMM (z: 0=q swizzled, 1=k swizzled, 2=v transposed/swizzled) ---
__global__ __launch_bounds__(256, 2)
void qkv_gemm(const short* __restrict__ from_bf, const short* __restrict__ to_bf,
              const short* __restrict__ WqT, const short* __restrict__ WkT,
              const short* __restrict__ WvT, const float* __restrict__ bv,
              short* __restrict__ q_swz, short* __restrict__ k_swz, short* __restrict__ vTs) {
  __shared__ __align__(16) short As[128][64];
  __shared__ __align__(16) short Bs[128][64];
  int mode = blockIdx.z;
  const short* A = (mode == 0) ? from_bf : to_bf;
  const short* B = (mode == 0) ? WqT : (mode == 1) ? WkT : WvT;
  int m0 = blockIdx.x * 128, n0 = blockIdx.y * 128;
  int tid = threadIdx.x;
  int w = tid >> 6, l = tid & 63;
  int wr = w >> 1, wc = w & 1;
  f32x4 acc[4][4] = {};
  for (int k0 = 0; k0 < 1024; k0 += 64) {
    __syncthreads();
#pragma unroll
    for (int i = 0; i < 4; ++i) {
      int off = i * 4096 + tid * 16;
      int r = off >> 7, cb_ = off & 127;
      g2l16(A + ((size_t)(m0 + r) << 10) + k0 + (cb_ >> 1), (short*)As + (off >> 1));
      g2l16(B + ((size_t)(n0 + r) << 10) + k0 + (cb_ >> 1), (short*)Bs + (off >> 1));
    }
    __syncthreads();
#pragma unroll
    for (int ks = 0; ks < 2; ++ks) {
      s16x8 af[4], bfr[4];
#pragma unroll
      for (int m = 0; m < 4; ++m)
        af[m] = *(const s16x8*)&As[wr * 64 + m * 16 + (l & 15)][ks * 32 + (l >> 4) * 8];
#pragma unroll
      for (int n = 0; n < 4; ++n)
        bfr[n] = *(const s16x8*)&Bs[wc * 64 + n * 16 + (l & 15)][ks * 32 + (l >> 4) * 8];
#pragma unroll
      for (int m = 0; m < 4; ++m)
#pragma unroll
        for (int n = 0; n < 4; ++n)
          acc[m][n] = MFMA(af[m], bfr[n], acc[m][n]);
    }
  }
  int lr = (l >> 4) * 4, lc = l & 15;
#pragma unroll
  for (int m = 0; m < 4; ++m)
#pragma unroll
    for (int n = 0; n < 4; ++n) {
      int row = m0 + wr * 64 + m * 16 + lr;
      int col = n0 + wc * 64 + n * 16 + lc;
      if (mode == 0) {
#pragma unroll
        for (int r = 0; r < 4; ++r) {
          int rr = row + r;
          q_swz[(size_t)rr * 1024 + (col ^ ((rr & 7) << 3))] = f2bf(acc[m][n][r]);
        }
      } else if (mode == 1) {
#pragma unroll
        for (int r = 0; r < 4; ++r) {
          int rr = row + r;
          k_swz[(size_t)rr * 1024 + (col ^ ((rr & 7) << 3))] = f2bf(acc[m][n][r]);
        }
      } else {
        float b = bv[col];
#pragma unroll
        for (int r = 0; r < 4; ++r) {
          int rr = row + r;                             // t index
          int tsw = rr ^ ((col & 7) << 3);              // swizzle within 64-group
          vTs[(size_t)col * 2048 + tsw] = f2bf(acc[m][n][r] + b);
        }
      }
    }
}

// ---------------- final GEMM: C f32 = ctx @ WdT + bd + resid ----------------
__global__ __launch_bounds__(256, 2)
void gemm_out(const short* __restrict__ A, const short* __restrict__ B,
              const float* __restrict__ bias, const float* __restrict__ resid,
              float* __restrict__ Cout) {
  __shared__ __align__(16) short As[128][64];
  __shared__ __align__(16) short Bs[128][64];
  int m0 = blockIdx.x * 128, n0 = blockIdx.y * 128;
  int tid = threadIdx.x;
  int w = tid >> 6, l = tid & 63;
  int wr = w >> 1, wc = w & 1;
  f32x4 acc[4][4] = {};
  for (int k0 = 0; k0 < 1024; k0 += 64) {
    __syncthreads();
#pragma unroll
    for (int i = 0; i < 4; ++i) {
      int off = i * 4096 + tid * 16;
      int r = off >> 7, cb_ = off & 127;
      g2l16(A + ((size_t)(m0 + r) << 10) + k0 + (cb_ >> 1), (short*)As + (off >> 1));
      g2l16(B + ((size_t)(n0 + r) << 10) + k0 + (cb_ >> 1), (short*)Bs + (off >> 1));
    }
    __syncthreads();
#pragma unroll
    for (int ks = 0; ks < 2; ++ks) {
      s16x8 af[4], bfr[4];
#pragma unroll
      for (int m = 0; m < 4; ++m)
        af[m] = *(const s16x8*)&As[wr * 64 + m * 16 + (l & 15)][ks * 32 + (l >> 4) * 8];
#pragma unroll
      for (int n = 0; n < 4; ++n)
        bfr[n] = *(const s16x8*)&Bs[wc * 64 + n * 16 + (l & 15)][ks * 32 + (l >> 4) * 8];
#pragma unroll
      for (int m = 0; m < 4; ++m)
#pragma unroll
        for (int n = 0; n < 4; ++n)
          acc[m][n] = MFMA(af[m], bfr[n], acc[m][n]);
    }
  }
  int lr = (l >> 4) * 4, lc = l & 15;
#pragma unroll
  for (int m = 0; m < 4; ++m)
#pragma unroll
    for (int n = 0; n < 4; ++n) {
      int row = m0 + wr * 64 + m * 16 + lr;
      int col = n0 + wc * 64 + n * 16 + lc;
      float b = bias[col];
#pragma unroll
      for (int r = 0; r < 4; ++r)
        Cout[(size_t)(row + r) * 1024 + col] = acc[m][n][r] + b + resid[(size_t)(row + r) * 1024 + col];
    }
}

// ---------------- content bias (pre-scaled by 0.125) ----------------
__global__ void cb_kernel(const short* __restrict__ to_bf, const short* __restrict__ WcbT,
                          float* __restrict__ cbv) {
  __shared__ short Wl[16 * 1024];
  int tid = threadIdx.x;
  for (int i = tid; i < 2048; i += 256)
    ((s16x8*)Wl)[i] = ((const s16x8*)WcbT)[i];
  __syncthreads();
  int w = tid >> 6, l = tid & 63;
  int t = blockIdx.x * 4 + w;
  const s16x8* xr = (const s16x8*)(to_bf + ((size_t)t << 10) + l * 16);
  s16x8 x0 = xr[0], x1 = xr[1];
  float xf[16];
#pragma unroll
  for (int i = 0; i < 8; ++i) { xf[i] = bf2f(x0[i]); xf[8 + i] = bf2f(x1[i]); }
#pragma unroll
  for (int h = 0; h < 16; ++h) {
    const s16x8* wr_ = (const s16x8*)(Wl + h * 1024 + l * 16);
    s16x8 w0 = wr_[0], w1 = wr_[1];
    float acc = 0.f;
#pragma unroll
    for (int i = 0; i < 8; ++i) { acc += xf[i] * bf2f(w0[i]); acc += xf[8 + i] * bf2f(w1[i]); }
#pragma unroll
    for (int s = 32; s; s >>= 1) acc += __shfl_xor(acc, s);
    if (l == 0) cbv[(size_t)h * 2048 + t] = acc * 0.125f;
  }
}

// ---------------- flash attention v4: 8 waves, FBLK=256, TBLK=128, t-split=2 ----------------
// LDS (118KB): qmA@0(32K) qmB@32K ktA@64K(16K) ktB@80K vt@96K(16K) cbl@112K(4K f32) mixl@116K(2K)
// Pipeline: dbuf qm/kt, counted vmcnt (6 g2l per chunk, 2 for V), raw s_barrier.
// P-tile overlays qmB (per-wave 4KB) during PV, split in two t-halves.
__global__ __launch_bounds__(512, 2)
void attn_kernel(const short* __restrict__ q_swz, const short* __restrict__ k_swz,
                 const short* __restrict__ vTs, const short* __restrict__ mixbf,
                 const float* __restrict__ cbg, float* __restrict__ ctxp,
                 f32x2* __restrict__ mlb) {
  __shared__ __align__(16) char smem[120832];
  char* qmA = smem;          char* qmB = smem + 32768;
  char* ktA = smem + 65536;  char* ktB = smem + 81920;
  char* vt  = smem + 98304;
  float* cbl  = (float*)(smem + 114688);
  short* mixl = (short*)(smem + 118784);
  const int f0 = blockIdx.x * 256, h = blockIdx.y, ts = blockIdx.z;
  const int tb = ts << 10;
  const int tid = threadIdx.x, w = tid >> 6, l = tid & 63;
  const int lr = l >> 4, lc = l & 15;
  const int swz = (lc & 7) << 4;

  for (int i = tid; i < 1024; i += 512) cbl[i] = cbg[h * 2048 + tb + i];
  for (int i = tid; i < 128; i += 512)
    ((s16x8*)mixl)[i] = ((const s16x8*)(mixbf + ((size_t)h << 10)))[i];
  __syncthreads();

#define ISSUE_QK(qmb, ktb, k0e, trow0)                                                   \
  do {                                                                                   \
    _Pragma("unroll") for (int i_ = 0; i_ < 4; ++i_) {                                   \
      int off_ = i_ * 8192 + tid * 16;                                                   \
      g2l16(q_swz + ((size_t)(f0 + (off_ >> 7)) << 10) + (k0e) + ((off_ & 127) >> 1),    \
            (qmb) + off_);                                                               \
    }                                                                                    \
    _Pragma("unroll") for (int i_ = 0; i_ < 2; ++i_) {                                   \
      int off_ = i_ * 8192 + tid * 16;                                                   \
      g2l16(k_swz + ((size_t)((trow0) + (off_ >> 7)) << 10) + (k0e) + ((off_ & 127) >> 1), \
            (ktb) + off_);                                                               \
    }                                                                                    \
  } while (0)

  // prologue: chunk 0 of t0=0
  ISSUE_QK(qmA, ktA, 0, tb);

  float m_run[8], l_run[8];
#pragma unroll
  for (int s2 = 0; s2 < 8; ++s2) { m_run[s2] = -1e30f; l_run[s2] = 0.f; }
  f32x4 ctx[2][4] = {};

  for (int t0 = 0; t0 < 1024; t0 += 128) {
    // V tile for this t0 (single-buffered; prev PV finished before end-of-t0 barrier)
#pragma unroll
    for (int i = 0; i < 2; ++i) {
      int off = i * 8192 + tid * 16;
      g2l16(vTs + ((size_t)(h * 64 + (off >> 8)) << 11) + tb + t0 + ((off & 255) >> 1), vt + off);
    }
    f32x4 sacc[2][8] = {};
    for (int c = 0; c < 16; ++c) {
      char* qmb = (c & 1) ? qmB : qmA;
      char* ktb = (c & 1) ? ktB : ktA;
      if (c < 15) {
        ISSUE_QK((c & 1) ? qmA : qmB, (c & 1) ? ktA : ktB, (c + 1) * 64, tb + t0);
      } else if (t0 < 896) {
        ISSUE_QK(qmA, ktA, 0, tb + t0 + 128);
      }
      if (c == 0) { VMCNT(8); }
      else if (c == 15 && t0 == 896) { VMCNT(0); }
      else { VMCNT(6); }
      BARRIER();
      const int k0b = c << 7;              // byte offset of this chunk's k-range in mixl
#pragma unroll
      for (int ks = 0; ks < 2; ++ks) {
        int xr = ks * 64 + lr * 16;
        s16x8 mx = *(const s16x8*)((char*)mixl + k0b + xr);
        float mf[8];
#pragma unroll
        for (int e = 0; e < 8; ++e) mf[e] = bf2f(mx[e]);
        s16x8 qv = *(const s16x8*)(qmb + ((w * 32 + lc) << 7) + (xr ^ swz));
        s16x8 qw = *(const s16x8*)(qmb + ((w * 32 + 16 + lc) << 7) + (xr ^ swz));
        s16x8 af0, af1;
#pragma unroll
        for (int e = 0; e < 8; ++e) {
          af0[e] = f2bf(bf2f(qv[e]) * mf[e]);
          af1[e] = f2bf(bf2f(qw[e]) * mf[e]);
        }
        __builtin_amdgcn_s_setprio(1);
#pragma unroll
        for (int n = 0; n < 8; ++n) {
          s16x8 bfr = *(const s16x8*)(ktb + ((n * 16 + lc) << 7) + (xr ^ swz));
          sacc[0][n] = MFMA(af0, bfr, sacc[0][n]);
          sacc[1][n] = MFMA(af1, bfr, sacc[1][n]);
        }
        __builtin_amdgcn_s_setprio(0);
      }
      BARRIER();
    }
    // ---- online softmax (slot s2=m*4+r owns f-row w*32+m*16+lr*4+r)
    float pm[8];
#pragma unroll
    for (int s2 = 0; s2 < 8; ++s2) pm[s2] = -1e30f;
#pragma unroll
    for (int m = 0; m < 2; ++m)
#pragma unroll
      for (int n = 0; n < 8; ++n) {
        float cbv = cbl[t0 + n * 16 + lc];
#pragma unroll
        for (int r = 0; r < 4; ++r) {
          float s = sacc[m][n][r] + cbv;
          sacc[m][n][r] = s;
          pm[m * 4 + r] = fmaxf(pm[m * 4 + r], s);
        }
      }
#pragma unroll
    for (int s_ = 1; s_ < 16; s_ <<= 1)
#pragma unroll
      for (int s2 = 0; s2 < 8; ++s2) pm[s2] = fmaxf(pm[s2], __shfl_xor(pm[s2], s_));
    float tsum[8];
#pragma unroll
    for (int s2 = 0; s2 < 8; ++s2) {
      float mnew = fmaxf(m_run[s2], pm[s2]);
      float corr = __expf(m_run[s2] - mnew);
      m_run[s2] = mnew; l_run[s2] *= corr; tsum[s2] = 0.f;
      int m = s2 >> 2, r = s2 & 3;
#pragma unroll
      for (int n2 = 0; n2 < 4; ++n2) ctx[m][n2][r] *= corr;
    }
#pragma unroll
    for (int m = 0; m < 2; ++m)
#pragma unroll
      for (int n = 0; n < 8; ++n)
#pragma unroll
        for (int r = 0; r < 4; ++r) {
          float e = __expf(sacc[m][n][r] - m_run[m * 4 + r]);
          sacc[m][n][r] = e;
          tsum[m * 4 + r] += e;
        }
#pragma unroll
    for (int s_ = 1; s_ < 16; s_ <<= 1)
#pragma unroll
      for (int s2 = 0; s2 < 8; ++s2) tsum[s2] += __shfl_xor(tsum[s2], s_);
#pragma unroll
    for (int s2 = 0; s2 < 8; ++s2) l_run[s2] += tsum[s2];
    // ---- P (per-wave 4KB in qmB) + PV, two t-halves of 64
    char* ptw = qmB + w * 4096;
#pragma unroll
    for (int hh = 0; hh < 2; ++hh) {
#pragma unroll
      for (int m = 0; m < 2; ++m)
#pragma unroll
        for (int nn = 0; nn < 4; ++nn)
#pragma unroll
          for (int r = 0; r < 4; ++r) {
            int row = m * 16 + lr * 4 + r;
            *(short*)(ptw + (row << 7) + ((((nn * 16 + lc) << 1)) ^ ((row & 7) << 4))) =
                f2bf(sacc[m][hh * 4 + nn][r]);
          }
#pragma unroll
      for (int ks = 0; ks < 2; ++ks) {
        s16x8 paf0 = *(const s16x8*)(ptw + (lc << 7) + ((ks * 64 + lr * 16) ^ swz));
        s16x8 paf1 = *(const s16x8*)(ptw + ((16 + lc) << 7) + ((ks * 64 + lr * 16) ^ swz));
#pragma unroll
        for (int n2 = 0; n2 < 4; ++n2) {
          s16x8 vb = *(const s16x8*)(vt + ((n2 * 16 + lc) << 8) +
                                     ((hh * 128 + ks * 64 + lr * 16) ^ swz));
          ctx[0][n2] = MFMA(paf0, vb, ctx[0][n2]);
          ctx[1][n2] = MFMA(paf1, vb, ctx[1][n2]);
        }
      }
    }
    BARRIER();   // protect vt + qmB before next t0's staging
  }
  // ---- write partials (unnormalized ctx, m, l)
  const int pb = (h * 2 + ts) * 2048;
#pragma unroll
  for (int m = 0; m < 2; ++m)
#pragma unroll
    for (int n2 = 0; n2 < 4; ++n2)
#pragma unroll
      for (int r = 0; r < 4; ++r) {
        int f = f0 + w * 32 + m * 16 + lr * 4 + r;
        ctxp[((size_t)(pb + f) << 6) + n2 * 16 + lc] = ctx[m][n2][r];
      }
  if (lc == 0) {
#pragma unroll
    for (int s2 = 0; s2 < 8; ++s2) {
      int f = f0 + w * 32 + (s2 >> 2) * 16 + lr * 4 + (s2 & 3);
      f32x2 v; v[0] = m_run[s2]; v[1] = l_run[s2];
      mlb[pb + f] = v;
    }
  }
#undef ISSUE_QK
}

// ---------------- combine the two t-split partials ----------------
__global__ void combine_kernel(const float* __restrict__ ctxp, const f32x2* __restrict__ mlb,
                               short* __restrict__ ctx_bf) {
  int f = blockIdx.x, tid = threadIdx.x;
  int h = tid >> 4, d4 = (tid & 15) * 4;
  f32x2 a = mlb[(h * 2 + 0) * 2048 + f];
  f32x2 b = mlb[(h * 2 + 1) * 2048 + f];
  float m = fmaxf(a[0], b[0]);
  float e0 = __expf(a[0] - m), e1 = __expf(b[0] - m);
  float inv = 1.f / (a[1] * e0 + b[1] * e1);
  f32x4 c0 = *(const f32x4*)(ctxp + (((size_t)(h * 2 + 0) * 2048 + f) << 6) + d4);
  f32x4 c1 = *(const f32x4*)(ctxp + (((size_t)(h * 2 + 1) * 2048 + f) << 6) + d4);
  s16x4 o;
#pragma unroll
  for (int i = 0; i < 4; ++i) o[i] = f2bf((c0[i] * e0 + c1[i] * e1) * inv);
  *(s16x4*)(ctx_bf + ((size_t)f << 10) + h * 64 + d4) = o;
}

// ---------------- LayerNorm (in-place) ----------------
__global__ void ln_kernel(const float* __restrict__ res, const float* __restrict__ gamma,
                          const float* __restrict__ beta, float* __restrict__ out) {
  int row = blockIdx.x, tid = threadIdx.x;
  f32x4 x = *(const f32x4*)(res + ((size_t)row << 10) + tid * 4);
  float s = x[0] + x[1] + x[2] + x[3];
  float s2 = x[0] * x[0] + x[1] * x[1] + x[2] * x[2] + x[3] * x[3];
#pragma unroll
  for (int m = 1; m < 64; m <<= 1) { s += __shfl_xor(s, m); s2 += __shfl_xor(s2, m); }
  __shared__ float red[8];
  int w = tid >> 6, l = tid & 63;
  if (l == 0) { red[w] = s; red[4 + w] = s2; }
  __syncthreads();
  s = red[0] + red[1] + red[2] + red[3];
  s2 = red[4] + red[5] + red[6] + red[7];
  float mu = s * (1.f / 1024.f);
  float var = s2 * (1.f / 1024.f) - mu * mu;
  float rstd = rsqrtf(var + 1e-5f);
  f32x4 o;
#pragma unroll
  for (int i = 0; i < 4; ++i)
    o[i] = (x[i] - mu) * rstd * gamma[tid * 4 + i] + beta[tid * 4 + i];
  *(f32x4*)(out + ((size_t)row << 10) + tid * 4) = o;
}

// ---------------- launch ----------------
extern "C" void kernel_launch(void* const* d_in, const int* in_sizes, int n_in,
                              void* d_out, int out_size, void* d_ws, size_t ws_size,
                              hipStream_t stream) {
  const float* hidden = (const float*)d_in[0];
  const int*   fpos   = (const int*)d_in[1];
  const int*   tpos   = (const int*)d_in[2];
  const float* Wq     = (const float*)d_in[3];
  const float* Wk     = (const float*)d_in[4];
  const float* Wcb    = (const float*)d_in[5];
  const float* Wv     = (const float*)d_in[6];
  const float* bv     = (const float*)d_in[7];
  const float* mixing = (const float*)d_in[8];
  const float* Wd     = (const float*)d_in[9];
  const float* bd     = (const float*)d_in[10];
  const float* gamma  = (const float*)d_in[11];
  const float* beta   = (const float*)d_in[12];

  char* p = (char*)d_ws;
  auto alloc = [&](size_t bytes) { char* r = p; p += (bytes + 255) & ~(size_t)255; return r; };
  float* from_f  = (float*)alloc((size_t)2048 * 1024 * 4);
  short* from_bf = (short*)alloc((size_t)2048 * 1024 * 2);
  short* to_bf   = (short*)alloc((size_t)2048 * 1024 * 2);
  short* WqT     = (short*)alloc((size_t)1024 * 1024 * 2);
  short* WkT     = (short*)alloc((size_t)1024 * 1024 * 2);
  short* WvT     = (short*)alloc((size_t)1024 * 1024 * 2);
  short* WdT     = (short*)alloc((size_t)1024 * 1024 * 2);
  short* WcbT    = (short*)alloc((size_t)16 * 1024 * 2);
  short* mixbf   = (short*)alloc((size_t)16 * 1024 * 2);
  short* q_swz   = (short*)alloc((size_t)2048 * 1024 * 2);
  short* k_swz   = (short*)alloc((size_t)2048 * 1024 * 2);
  short* vTs     = (short*)alloc((size_t)1024 * 2048 * 2);
  float* cbb     = (float*)alloc((size_t)16 * 2048 * 4);
  short* ctx_bf  = (short*)alloc((size_t)2048 * 1024 * 2);
  float* ctxp    = (float*)alloc((size_t)32 * 2048 * 64 * 4);
  f32x2* mlb     = (f32x2*)alloc((size_t)32 * 2048 * 8);

  wtrans_kernel<<<dim3(16, 16, 4), 256, 0, stream>>>(Wq, Wk, Wv, Wd, WqT, WkT, WvT, WdT);
  smallconv_kernel<<<128, 256, 0, stream>>>(Wcb, mixing, WcbT, mixbf);
  gather_kernel<<<dim3(2048, 2), 256, 0, stream>>>(hidden, fpos, tpos, from_f, from_bf, to_bf);
  qkv_gemm<<<dim3(16, 8, 3), 256, 0, stream>>>(from_bf, to_bf, WqT, WkT, WvT, bv,
                                               q_swz, k_swz, vTs);
  cb_kernel<<<512, 256, 0, stream>>>(to_bf, WcbT, cbb);
  attn_kernel<<<dim3(8, 16, 2), 512, 0, stream>>>(q_swz, k_swz, vTs, mixbf, cbb, ctxp, mlb);
  combine_kernel<<<2048, 256, 0, stream>>>(ctxp, mlb, ctx_bf);
  gemm_out<<<dim3(16, 8), 256, 0, stream>>>(ctx_bf, WdT, bd, from_f, (float*)d_out);
  ln_kernel<<<2048, 256, 0, stream>>>((float*)d_out, gamma, beta, (float*)d_out);
}

// Round 5
// 350.728 us; speedup vs baseline: 1.7939x; 1.1241x over previous
//
#include <hip/hip_runtime.h>
#include <stdint.h>
#include <math.h>

// ---------------- types & helpers ----------------
typedef float    f32x4 __attribute__((ext_vector_type(4)));
typedef float    f32x2 __attribute__((ext_vector_type(2)));
typedef short    s16x8 __attribute__((ext_vector_type(8)));
typedef short    s16x4 __attribute__((ext_vector_type(4)));
typedef unsigned u32x4 __attribute__((ext_vector_type(4)));

#define SCALE_LOG2E 0.1803368751839806f   // 0.125 * log2(e)

__device__ __forceinline__ float bf2f(short s) {
  unsigned u = ((unsigned)(unsigned short)s) << 16;
  return __builtin_bit_cast(float, u);
}
__device__ __forceinline__ short f2bf(float f) {
  unsigned u = __builtin_bit_cast(unsigned, f);
  u = u + 0x7fffu + ((u >> 16) & 1u);   // RNE
  return (short)(u >> 16);
}
// pack two f32 -> two bf16 (RNE) in one instruction
__device__ __forceinline__ unsigned cvtpk(float lo, float hi) {
  unsigned r;
  asm("v_cvt_pk_bf16_f32 %0, %1, %2" : "=v"(r) : "v"(lo), "v"(hi));
  return r;
}
__device__ __forceinline__ void g2l16(const void* g, void* l) {
  __builtin_amdgcn_global_load_lds((const __attribute__((address_space(1))) void*)g,
                                   (__attribute__((address_space(3))) void*)l,
                                   16, 0, 0);
}
#define BARRIER() do { __builtin_amdgcn_s_barrier(); __builtin_amdgcn_sched_barrier(0); } while (0)
#define VMCNT(N)  asm volatile("s_waitcnt vmcnt(" #N ")" ::: "memory")
#define MFMA(a, b, c) __builtin_amdgcn_mfma_f32_16x16x32_bf16(a, b, c, 0, 0, 0)

// ---------------- prep: transpose 1024x1024 f32 weights -> bf16 [N][K] ----------------
__global__ void wtrans_kernel(const float* __restrict__ Wq, const float* __restrict__ Wk,
                              const float* __restrict__ Wv, const float* __restrict__ Wd,
                              short* __restrict__ WqT, short* __restrict__ WkT,
                              short* __restrict__ WvT, short* __restrict__ WdT) {
  __shared__ float tile[64][65];
  const float* src; short* dst;
  switch (blockIdx.z) {
    case 0: src = Wq; dst = WqT; break;
    case 1: src = Wk; dst = WkT; break;
    case 2: src = Wv; dst = WvT; break;
    default: src = Wd; dst = WdT; break;
  }
  int k0 = blockIdx.y * 64;
  int n0 = blockIdx.x * 64;
  int tid = threadIdx.x;
#pragma unroll
  for (int p = 0; p < 4; ++p) {
    int idx = p * 1024 + tid * 4;
    int r = idx >> 6, c = idx & 63;
    f32x4 v = *(const f32x4*)(src + (size_t)(k0 + r) * 1024 + n0 + c);
    tile[r][c + 0] = v[0]; tile[r][c + 1] = v[1];
    tile[r][c + 2] = v[2]; tile[r][c + 3] = v[3];
  }
  __syncthreads();
#pragma unroll
  for (int p = 0; p < 2; ++p) {
    int idx = p * 2048 + tid * 8;
    int r = idx >> 6, c = idx & 63;
    s16x8 o;
#pragma unroll
    for (int i = 0; i < 8; ++i) o[i] = f2bf(tile[c + i][r]);
    *(s16x8*)(dst + (size_t)(n0 + r) * 1024 + k0 + c) = o;
  }
}

// Wcb [1024][16] -> WcbT bf16 [16][1024]; mixing -> bf16 scaled by 0.125*log2(e)
__global__ void smallconv_kernel(const float* __restrict__ Wcb, const float* __restrict__ mixing,
                                 short* __restrict__ WcbT, short* __restrict__ mixbf) {
  int idx = blockIdx.x * 256 + threadIdx.x;
  if (idx < 16384) {
    int h = idx >> 10, d = idx & 1023;
    WcbT[idx] = f2bf(Wcb[d * 16 + h]);
  } else {
    int j = idx - 16384;
    mixbf[j] = f2bf(mixing[j] * SCALE_LOG2E);
  }
}

__global__ void gather_kernel(const float* __restrict__ hidden, const int* __restrict__ fpos,
                              const int* __restrict__ tpos, float* __restrict__ from_f,
                              short* __restrict__ from_bf, short* __restrict__ to_bf) {
  int row = blockIdx.x;
  int c = threadIdx.x * 4;
  if (blockIdx.y == 0) {
    int src = fpos[row] & 511;
    f32x4 v = *(const f32x4*)(hidden + (size_t)src * 1024 + c);
    *(f32x4*)(from_f + (size_t)row * 1024 + c) = v;
    s16x4 o;
#pragma unroll
    for (int i = 0; i < 4; ++i) o[i] = f2bf(v[i]);
    *(s16x4*)(from_bf + (size_t)row * 1024 + c) = o;
  } else {
    int src = tpos[row] & 511;
    f32x4 v = *(const f32x4*)(hidden + (size_t)src * 1024 + c);
    s16x4 o;
#pragma unroll
    for (int i = 0; i < 4; ++i) o[i] = f2bf(v[i]);
    *(s16x4*)(to_bf + (size_t)row * 1024 + c) = o;
  }
}

// ---------------- merged QKV GEMM (z: 0=q swizzled, 1=k swizzled, 2=v transposed/swizzled) ---
__global__ __launch_bounds__(256, 2)
void qkv_gemm(const short* __restrict__ from_bf, const short* __restrict__ to_bf,
              const short* __restrict__ WqT, const short* __restrict__ WkT,
              const short* __restrict__ WvT, const float* __restrict__ bv,
              short* __restrict__ q_swz, short* __restrict__ k_swz, short* __restrict__ vTs) {
  __shared__ __align__(16) short As[128][64];
  __shared__ __align__(16) short Bs[128][64];
  int mode = blockIdx.z;
  const short* A = (mode == 0) ? from_bf : to_bf;
  const short* B = (mode == 0) ? WqT : (mode == 1) ? WkT : WvT;
  int m0 = blockIdx.x * 128, n0 = blockIdx.y * 128;
  int tid = threadIdx.x;
  int w = tid >> 6, l = tid & 63;
  int wr = w >> 1, wc = w & 1;
  f32x4 acc[4][4] = {};
  for (int k0 = 0; k0 < 1024; k0 += 64) {
    __syncthreads();
#pragma unroll
    for (int i = 0; i < 4; ++i) {
      int off = i * 4096 + tid * 16;
      int r = off >> 7, cb_ = off & 127;
      g2l16(A + ((size_t)(m0 + r) << 10) + k0 + (cb_ >> 1), (short*)As + (off >> 1));
      g2l16(B + ((size_t)(n0 + r) << 10) + k0 + (cb_ >> 1), (short*)Bs + (off >> 1));
    }
    __syncthreads();
#pragma unroll
    for (int ks = 0; ks < 2; ++ks) {
      s16x8 af[4], bfr[4];
#pragma unroll
      for (int m = 0; m < 4; ++m)
        af[m] = *(const s16x8*)&As[wr * 64 + m * 16 + (l & 15)][ks * 32 + (l >> 4) * 8];
#pragma unroll
      for (int n = 0; n < 4; ++n)
        bfr[n] = *(const s16x8*)&Bs[wc * 64 + n * 16 + (l & 15)][ks * 32 + (l >> 4) * 8];
#pragma unroll
      for (int m = 0; m < 4; ++m)
#pragma unroll
        for (int n = 0; n < 4; ++n)
          acc[m][n] = MFMA(af[m], bfr[n], acc[m][n]);
    }
  }
  int lr = (l >> 4) * 4, lc = l & 15;
#pragma unroll
  for (int m = 0; m < 4; ++m)
#pragma unroll
    for (int n = 0; n < 4; ++n) {
      int row = m0 + wr * 64 + m * 16 + lr;
      int col = n0 + wc * 64 + n * 16 + lc;
      if (mode == 0) {
#pragma unroll
        for (int r = 0; r < 4; ++r) {
          int rr = row + r;
          q_swz[(size_t)rr * 1024 + (col ^ ((rr & 7) << 3))] = f2bf(acc[m][n][r]);
        }
      } else if (mode == 1) {
#pragma unroll
        for (int r = 0; r < 4; ++r) {
          int rr = row + r;
          k_swz[(size_t)rr * 1024 + (col ^ ((rr & 7) << 3))] = f2bf(acc[m][n][r]);
        }
      } else {
        float b = bv[col];
#pragma unroll
        for (int r = 0; r < 4; ++r) {
          int rr = row + r;                             // t index
          int tsw = rr ^ ((col & 7) << 3);              // swizzle within 64-group
          vTs[(size_t)col * 2048 + tsw] = f2bf(acc[m][n][r] + b);
        }
      }
    }
}

// ---------------- final GEMM: C f32 = ctx @ WdT + bd + resid ----------------
__global__ __launch_bounds__(256, 2)
void gemm_out(const short* __restrict__ A, const short* __restrict__ B,
              const float* __restrict__ bias, const float* __restrict__ resid,
              float* __restrict__ Cout) {
  __shared__ __align__(16) short As[128][64];
  __shared__ __align__(16) short Bs[128][64];
  int m0 = blockIdx.x * 128, n0 = blockIdx.y * 128;
  int tid = threadIdx.x;
  int w = tid >> 6, l = tid & 63;
  int wr = w >> 1, wc = w & 1;
  f32x4 acc[4][4] = {};
  for (int k0 = 0; k0 < 1024; k0 += 64) {
    __syncthreads();
#pragma unroll
    for (int i = 0; i < 4; ++i) {
      int off = i * 4096 + tid * 16;
      int r = off >> 7, cb_ = off & 127;
      g2l16(A + ((size_t)(m0 + r) << 10) + k0 + (cb_ >> 1), (short*)As + (off >> 1));
      g2l16(B + ((size_t)(n0 + r) << 10) + k0 + (cb_ >> 1), (short*)Bs + (off >> 1));
    }
    __syncthreads();
#pragma unroll
    for (int ks = 0; ks < 2; ++ks) {
      s16x8 af[4], bfr[4];
#pragma unroll
      for (int m = 0; m < 4; ++m)
        af[m] = *(const s16x8*)&As[wr * 64 + m * 16 + (l & 15)][ks * 32 + (l >> 4) * 8];
#pragma unroll
      for (int n = 0; n < 4; ++n)
        bfr[n] = *(const s16x8*)&Bs[wc * 64 + n * 16 + (l & 15)][ks * 32 + (l >> 4) * 8];
#pragma unroll
      for (int m = 0; m < 4; ++m)
#pragma unroll
        for (int n = 0; n < 4; ++n)
          acc[m][n] = MFMA(af[m], bfr[n], acc[m][n]);
    }
  }
  int lr = (l >> 4) * 4, lc = l & 15;
#pragma unroll
  for (int m = 0; m < 4; ++m)
#pragma unroll
    for (int n = 0; n < 4; ++n) {
      int row = m0 + wr * 64 + m * 16 + lr;
      int col = n0 + wc * 64 + n * 16 + lc;
      float b = bias[col];
#pragma unroll
      for (int r = 0; r < 4; ++r)
        Cout[(size_t)(row + r) * 1024 + col] = acc[m][n][r] + b + resid[(size_t)(row + r) * 1024 + col];
    }
}

// ---------------- content bias (pre-scaled by 0.125*log2e) ----------------
__global__ void cb_kernel(const short* __restrict__ to_bf, const short* __restrict__ WcbT,
                          float* __restrict__ cbv) {
  __shared__ short Wl[16 * 1024];
  int tid = threadIdx.x;
  for (int i = tid; i < 2048; i += 256)
    ((s16x8*)Wl)[i] = ((const s16x8*)WcbT)[i];
  __syncthreads();
  int w = tid >> 6, l = tid & 63;
  int t = blockIdx.x * 4 + w;
  const s16x8* xr = (const s16x8*)(to_bf + ((size_t)t << 10) + l * 16);
  s16x8 x0 = xr[0], x1 = xr[1];
  float xf[16];
#pragma unroll
  for (int i = 0; i < 8; ++i) { xf[i] = bf2f(x0[i]); xf[8 + i] = bf2f(x1[i]); }
#pragma unroll
  for (int h = 0; h < 16; ++h) {
    const s16x8* wr_ = (const s16x8*)(Wl + h * 1024 + l * 16);
    s16x8 w0 = wr_[0], w1 = wr_[1];
    float acc = 0.f;
#pragma unroll
    for (int i = 0; i < 8; ++i) { acc += xf[i] * bf2f(w0[i]); acc += xf[8 + i] * bf2f(w1[i]); }
#pragma unroll
    for (int s = 32; s; s >>= 1) acc += __shfl_xor(acc, s);
    if (l == 0) cbv[(size_t)h * 2048 + t] = acc * SCALE_LOG2E;
  }
}

// qmix[h][f][d'] = q_swz[f][d'] * mix_scaled[h][d' ^ ((f&7)<<3)]  (stays q-swizzled layout)
__global__ void qmix_kernel(const short* __restrict__ q_swz, const short* __restrict__ mixbf,
                            short* __restrict__ qmix) {
  int f = blockIdx.x, h = blockIdx.y;
  int c = threadIdx.x * 8;
  int fs = (f & 7) << 3;
  s16x8 qv = *(const s16x8*)(q_swz + ((size_t)f << 10) + c);
  s16x8 mv = *(const s16x8*)(mixbf + ((size_t)h << 10) + (c ^ fs));
  u32x4 o;
#pragma unroll
  for (int e2 = 0; e2 < 4; ++e2)
    o[e2] = cvtpk(bf2f(qv[2 * e2]) * bf2f(mv[2 * e2]),
                  bf2f(qv[2 * e2 + 1]) * bf2f(mv[2 * e2 + 1]));
  *(s16x8*)(qmix + (((size_t)h * 2048 + f) << 10) + c) = __builtin_bit_cast(s16x8, o);
}

// ---------------- flash attention v5: 8 waves, FBLK=256, TBLK=128, t-split=2 ----------------
// LDS (118KB): qmA@0(32K) qmB@32K ktA@64K(16K) ktB@80K vt@96K(16K) cbl@112K(4K f32) mixl@116K(2K)
// QMIX=1: A-frags read directly (q*mix precomputed in global). QMIX=0: cvt_pk repack at read.
template <bool QMIX>
__global__ __launch_bounds__(512, 2)
void attn_kernel(const short* __restrict__ qsrc, const short* __restrict__ k_swz,
                 const short* __restrict__ vTs, const short* __restrict__ mixbf,
                 const float* __restrict__ cbg, float* __restrict__ ctxp,
                 f32x2* __restrict__ mlb) {
  __shared__ __align__(16) char smem[120832];
  char* qmA = smem;          char* qmB = smem + 32768;
  char* ktA = smem + 65536;  char* ktB = smem + 81920;
  char* vt  = smem + 98304;
  float* cbl  = (float*)(smem + 114688);
  short* mixl = (short*)(smem + 118784);
  const int f0 = blockIdx.x * 256, h = blockIdx.y, ts = blockIdx.z;
  const int tb = ts << 10;
  const int tid = threadIdx.x, w = tid >> 6, l = tid & 63;
  const int lr = l >> 4, lc = l & 15;
  const int swz = (lc & 7) << 4;

  for (int i = tid; i < 1024; i += 512) cbl[i] = cbg[h * 2048 + tb + i];
  if (!QMIX)
    for (int i = tid; i < 128; i += 512)
      ((s16x8*)mixl)[i] = ((const s16x8*)(mixbf + ((size_t)h << 10)))[i];
  __syncthreads();

  const short* qrow = QMIX ? qsrc + (((size_t)h * 2048 + f0) << 10)
                           : qsrc + ((size_t)f0 << 10);

#define ISSUE_QK(qmb, ktb, k0e, trow0)                                                     \
  do {                                                                                     \
    _Pragma("unroll") for (int i_ = 0; i_ < 4; ++i_) {                                     \
      int off_ = i_ * 8192 + tid * 16;                                                     \
      g2l16(qrow + ((size_t)(off_ >> 7) << 10) + (k0e) + ((off_ & 127) >> 1),              \
            (qmb) + off_);                                                                 \
    }                                                                                      \
    _Pragma("unroll") for (int i_ = 0; i_ < 2; ++i_) {                                     \
      int off_ = i_ * 8192 + tid * 16;                                                     \
      g2l16(k_swz + ((size_t)((trow0) + (off_ >> 7)) << 10) + (k0e) + ((off_ & 127) >> 1), \
            (ktb) + off_);                                                                 \
    }                                                                                      \
  } while (0)

  // prologue: chunk 0 of t0=0
  ISSUE_QK(qmA, ktA, 0, tb);

  float m_run[8], l_run[8];
#pragma unroll
  for (int s2 = 0; s2 < 8; ++s2) { m_run[s2] = -1e30f; l_run[s2] = 0.f; }
  f32x4 ctx[2][4] = {};

  for (int t0 = 0; t0 < 1024; t0 += 128) {
    // V tile for this t0 (single-buffered; prev PV done before end-of-t0 barrier)
#pragma unroll
    for (int i = 0; i < 2; ++i) {
      int off = i * 8192 + tid * 16;
      g2l16(vTs + ((size_t)(h * 64 + (off >> 8)) << 11) + tb + t0 + ((off & 255) >> 1), vt + off);
    }
    f32x4 sacc[2][8] = {};
    for (int c = 0; c < 16; ++c) {
      char* qmb = (c & 1) ? qmB : qmA;
      char* ktb = (c & 1) ? ktB : ktA;
      if (c < 15) {
        ISSUE_QK((c & 1) ? qmA : qmB, (c & 1) ? ktA : ktB, (c + 1) * 64, tb + t0);
      } else if (t0 < 896) {
        ISSUE_QK(qmA, ktA, 0, tb + t0 + 128);
      }
      if (c == 0) { VMCNT(8); }
      else if (c == 15 && t0 == 896) { VMCNT(0); }
      else { VMCNT(6); }
      BARRIER();
      const int k0b = c << 7;              // byte offset of chunk's k-range in mixl
#pragma unroll
      for (int ks = 0; ks < 2; ++ks) {
        int xr = ks * 64 + lr * 16;
        s16x8 af0, af1;
        if (QMIX) {
          af0 = *(const s16x8*)(qmb + ((w * 32 + lc) << 7) + (xr ^ swz));
          af1 = *(const s16x8*)(qmb + ((w * 32 + 16 + lc) << 7) + (xr ^ swz));
        } else {
          s16x8 mx = *(const s16x8*)((char*)mixl + k0b + xr);
          s16x8 qv = *(const s16x8*)(qmb + ((w * 32 + lc) << 7) + (xr ^ swz));
          s16x8 qw = *(const s16x8*)(qmb + ((w * 32 + 16 + lc) << 7) + (xr ^ swz));
          u32x4 a0u, a1u;
#pragma unroll
          for (int e2 = 0; e2 < 4; ++e2) {
            float m0 = bf2f(mx[2 * e2]), m1 = bf2f(mx[2 * e2 + 1]);
            a0u[e2] = cvtpk(bf2f(qv[2 * e2]) * m0, bf2f(qv[2 * e2 + 1]) * m1);
            a1u[e2] = cvtpk(bf2f(qw[2 * e2]) * m0, bf2f(qw[2 * e2 + 1]) * m1);
          }
          af0 = __builtin_bit_cast(s16x8, a0u);
          af1 = __builtin_bit_cast(s16x8, a1u);
        }
        __builtin_amdgcn_s_setprio(1);
#pragma unroll
        for (int n = 0; n < 8; ++n) {
          s16x8 bfr = *(const s16x8*)(ktb + ((n * 16 + lc) << 7) + (xr ^ swz));
          sacc[0][n] = MFMA(af0, bfr, sacc[0][n]);
          sacc[1][n] = MFMA(af1, bfr, sacc[1][n]);
        }
        __builtin_amdgcn_s_setprio(0);
      }
      BARRIER();
    }
    // ---- online softmax in exp2 domain (slot s2=m*4+r owns f-row w*32+m*16+lr*4+r)
    float pm[8];
#pragma unroll
    for (int s2 = 0; s2 < 8; ++s2) pm[s2] = -1e30f;
#pragma unroll
    for (int m = 0; m < 2; ++m)
#pragma unroll
      for (int n = 0; n < 8; ++n) {
        float cbv = cbl[t0 + n * 16 + lc];
#pragma unroll
        for (int r = 0; r < 4; ++r) {
          float s = sacc[m][n][r] + cbv;
          sacc[m][n][r] = s;
          pm[m * 4 + r] = fmaxf(pm[m * 4 + r], s);
        }
      }
#pragma unroll
    for (int s_ = 1; s_ < 16; s_ <<= 1)
#pragma unroll
      for (int s2 = 0; s2 < 8; ++s2) pm[s2] = fmaxf(pm[s2], __shfl_xor(pm[s2], s_));
    float tsum[8];
#pragma unroll
    for (int s2 = 0; s2 < 8; ++s2) {
      float mnew = fmaxf(m_run[s2], pm[s2]);
      float corr = exp2f(m_run[s2] - mnew);
      m_run[s2] = mnew; l_run[s2] *= corr; tsum[s2] = 0.f;
      int m = s2 >> 2, r = s2 & 3;
#pragma unroll
      for (int n2 = 0; n2 < 4; ++n2) ctx[m][n2][r] *= corr;
    }
#pragma unroll
    for (int m = 0; m < 2; ++m)
#pragma unroll
      for (int n = 0; n < 8; ++n)
#pragma unroll
        for (int r = 0; r < 4; ++r) {
          float e = exp2f(sacc[m][n][r] - m_run[m * 4 + r]);
          sacc[m][n][r] = e;
          tsum[m * 4 + r] += e;
        }
#pragma unroll
    for (int s_ = 1; s_ < 16; s_ <<= 1)
#pragma unroll
      for (int s2 = 0; s2 < 8; ++s2) tsum[s2] += __shfl_xor(tsum[s2], s_);
#pragma unroll
    for (int s2 = 0; s2 < 8; ++s2) l_run[s2] += tsum[s2];
    // ---- P (per-wave 4KB in qmB) + PV, two t-halves of 64
    char* ptw = qmB + w * 4096;
#pragma unroll
    for (int hh = 0; hh < 2; ++hh) {
#pragma unroll
      for (int m = 0; m < 2; ++m)
#pragma unroll
        for (int nn = 0; nn < 4; ++nn)
#pragma unroll
          for (int r = 0; r < 4; ++r) {
            int row = m * 16 + lr * 4 + r;
            *(short*)(ptw + (row << 7) + ((((nn * 16 + lc) << 1)) ^ ((row & 7) << 4))) =
                f2bf(sacc[m][hh * 4 + nn][r]);
          }
#pragma unroll
      for (int ks = 0; ks < 2; ++ks) {
        s16x8 paf0 = *(const s16x8*)(ptw + (lc << 7) + ((ks * 64 + lr * 16) ^ swz));
        s16x8 paf1 = *(const s16x8*)(ptw + ((16 + lc) << 7) + ((ks * 64 + lr * 16) ^ swz));
#pragma unroll
        for (int n2 = 0; n2 < 4; ++n2) {
          s16x8 vb = *(const s16x8*)(vt + ((n2 * 16 + lc) << 8) +
                                     ((hh * 128 + ks * 64 + lr * 16) ^ swz));
          ctx[0][n2] = MFMA(paf0, vb, ctx[0][n2]);
          ctx[1][n2] = MFMA(paf1, vb, ctx[1][n2]);
        }
      }
    }
    BARRIER();   // protect vt + qmB before next t0's staging
  }
  // ---- write partials (unnormalized ctx, m, l)
  const int pb = (h * 2 + ts) * 2048;
#pragma unroll
  for (int m = 0; m < 2; ++m)
#pragma unroll
    for (int n2 = 0; n2 < 4; ++n2)
#pragma unroll
      for (int r = 0; r < 4; ++r) {
        int f = f0 + w * 32 + m * 16 + lr * 4 + r;
        ctxp[((size_t)(pb + f) << 6) + n2 * 16 + lc] = ctx[m][n2][r];
      }
  if (lc == 0) {
#pragma unroll
    for (int s2 = 0; s2 < 8; ++s2) {
      int f = f0 + w * 32 + (s2 >> 2) * 16 + lr * 4 + (s2 & 3);
      f32x2 v; v[0] = m_run[s2]; v[1] = l_run[s2];
      mlb[pb + f] = v;
    }
  }
#undef ISSUE_QK
}

// ---------------- combine the two t-split partials (exp2 domain) ----------------
__global__ void combine_kernel(const float* __restrict__ ctxp, const f32x2* __restrict__ mlb,
                               short* __restrict__ ctx_bf) {
  int f = blockIdx.x, tid = threadIdx.x;
  int h = tid >> 4, d4 = (tid & 15) * 4;
  f32x2 a = mlb[(h * 2 + 0) * 2048 + f];
  f32x2 b = mlb[(h * 2 + 1) * 2048 + f];
  float m = fmaxf(a[0], b[0]);
  float e0 = exp2f(a[0] - m), e1 = exp2f(b[0] - m);
  float inv = 1.f / (a[1] * e0 + b[1] * e1);
  f32x4 c0 = *(const f32x4*)(ctxp + (((size_t)(h * 2 + 0) * 2048 + f) << 6) + d4);
  f32x4 c1 = *(const f32x4*)(ctxp + (((size_t)(h * 2 + 1) * 2048 + f) << 6) + d4);
  s16x4 o;
#pragma unroll
  for (int i = 0; i < 4; ++i) o[i] = f2bf((c0[i] * e0 + c1[i] * e1) * inv);
  *(s16x4*)(ctx_bf + ((size_t)f << 10) + h * 64 + d4) = o;
}

// ---------------- LayerNorm (in-place) ----------------
__global__ void ln_kernel(const float* __restrict__ res, const float* __restrict__ gamma,
                          const float* __restrict__ beta, float* __restrict__ out) {
  int row = blockIdx.x, tid = threadIdx.x;
  f32x4 x = *(const f32x4*)(res + ((size_t)row << 10) + tid * 4);
  float s = x[0] + x[1] + x[2] + x[3];
  float s2 = x[0] * x[0] + x[1] * x[1] + x[2] * x[2] + x[3] * x[3];
#pragma unroll
  for (int m = 1; m < 64; m <<= 1) { s += __shfl_xor(s, m); s2 += __shfl_xor(s2, m); }
  __shared__ float red[8];
  int w = tid >> 6, l = tid & 63;
  if (l == 0) { red[w] = s; red[4 + w] = s2; }
  __syncthreads();
  s = red[0] + red[1] + red[2] + red[3];
  s2 = red[4] + red[5] + red[6] + red[7];
  float mu = s * (1.f / 1024.f);
  float var = s2 * (1.f / 1024.f) - mu * mu;
  float rstd = rsqrtf(var + 1e-5f);
  f32x4 o;
#pragma unroll
  for (int i = 0; i < 4; ++i)
    o[i] = (x[i] - mu) * rstd * gamma[tid * 4 + i] + beta[tid * 4 + i];
  *(f32x4*)(out + ((size_t)row << 10) + tid * 4) = o;
}

// ---------------- launch ----------------
extern "C" void kernel_launch(void* const* d_in, const int* in_sizes, int n_in,
                              void* d_out, int out_size, void* d_ws, size_t ws_size,
                              hipStream_t stream) {
  const float* hidden = (const float*)d_in[0];
  const int*   fpos   = (const int*)d_in[1];
  const int*   tpos   = (const int*)d_in[2];
  const float* Wq     = (const float*)d_in[3];
  const float* Wk     = (const float*)d_in[4];
  const float* Wcb    = (const float*)d_in[5];
  const float* Wv     = (const float*)d_in[6];
  const float* bv     = (const float*)d_in[7];
  const float* mixing = (const float*)d_in[8];
  const float* Wd     = (const float*)d_in[9];
  const float* bd     = (const float*)d_in[10];
  const float* gamma  = (const float*)d_in[11];
  const float* beta   = (const float*)d_in[12];

  char* p = (char*)d_ws;
  auto alloc = [&](size_t bytes) { char* r = p; p += (bytes + 255) & ~(size_t)255; return r; };
  float* from_f  = (float*)alloc((size_t)2048 * 1024 * 4);
  short* from_bf = (short*)alloc((size_t)2048 * 1024 * 2);
  short* to_bf   = (short*)alloc((size_t)2048 * 1024 * 2);
  short* WqT     = (short*)alloc((size_t)1024 * 1024 * 2);
  short* WkT     = (short*)alloc((size_t)1024 * 1024 * 2);
  short* WvT     = (short*)alloc((size_t)1024 * 1024 * 2);
  short* WdT     = (short*)alloc((size_t)1024 * 1024 * 2);
  short* WcbT    = (short*)alloc((size_t)16 * 1024 * 2);
  short* mixbf   = (short*)alloc((size_t)16 * 1024 * 2);
  short* q_swz   = (short*)alloc((size_t)2048 * 1024 * 2);
  short* k_swz   = (short*)alloc((size_t)2048 * 1024 * 2);
  short* vTs     = (short*)alloc((size_t)1024 * 2048 * 2);
  float* cbb     = (float*)alloc((size_t)16 * 2048 * 4);
  short* ctx_bf  = (short*)alloc((size_t)2048 * 1024 * 2);
  float* ctxp    = (float*)alloc((size_t)32 * 2048 * 64 * 4);
  f32x2* mlb     = (f32x2*)alloc((size_t)32 * 2048 * 8);
  size_t used = (size_t)(p - (char*)d_ws);
  short* qmixb = (short*)p;
  bool use_qmix = ws_size >= used + (size_t)16 * 2048 * 1024 * 2;

  wtrans_kernel<<<dim3(16, 16, 4), 256, 0, stream>>>(Wq, Wk, Wv, Wd, WqT, WkT, WvT, WdT);
  smallconv_kernel<<<128, 256, 0, stream>>>(Wcb, mixing, WcbT, mixbf);
  gather_kernel<<<dim3(2048, 2), 256, 0, stream>>>(hidden, fpos, tpos, from_f, from_bf, to_bf);
  qkv_gemm<<<dim3(16, 8, 3), 256, 0, stream>>>(from_bf, to_bf, WqT, WkT, WvT, bv,
                                               q_swz, k_swz, vTs);
  cb_kernel<<<512, 256, 0, stream>>>(to_bf, WcbT, cbb);
  if (use_qmix) {
    qmix_kernel<<<dim3(2048, 16), 128, 0, stream>>>(q_swz, mixbf, qmixb);
    attn_kernel<true><<<dim3(8, 16, 2), 512, 0, stream>>>(qmixb, k_swz, vTs, mixbf, cbb, ctxp, mlb);
  } else {
    attn_kernel<false><<<dim3(8, 16, 2), 512, 0, stream>>>(q_swz, k_swz, vTs, mixbf, cbb, ctxp, mlb);
  }
  combine_kernel<<<2048, 256, 0, stream>>>(ctxp, mlb, ctx_bf);
  gemm_out<<<dim3(16, 8), 256, 0, stream>>>(ctx_bf, WdT, bd, from_f, (float*)d_out);
  ln_kernel<<<2048, 256, 0, stream>>>((float*)d_out, gamma, beta, (float*)d_out);
}